// Round 11
// baseline (1277.078 us; speedup 1.0000x reference)
//
#include <hip/hip_runtime.h>
#include <stdint.h>

#define NTOK 2048
#define CDIM 1024
#define ROWS 4096          // B*N
#define MODS_STRIDE 6144
#define INTERDIM 2816
#define NCHUNK 32
#define CHLEN (NTOK/NCHUNK)   // 64

typedef unsigned short u16;
typedef __bf16 bf16x8 __attribute__((ext_vector_type(8)));
typedef float f32x4 __attribute__((ext_vector_type(4)));
typedef float f32x16 __attribute__((ext_vector_type(16)));
typedef u16 u16x8 __attribute__((ext_vector_type(8)));
typedef unsigned int u32x4 __attribute__((ext_vector_type(4)));

__device__ __forceinline__ float b2f(u16 u){
  union { unsigned int i; float f; } v; v.i = ((unsigned int)u) << 16; return v.f;
}
__device__ __forceinline__ u16 f2b(float f){
  union { float f; unsigned int i; } v; v.f = f;
  unsigned int i = v.i;
  unsigned int r = i + 0x7FFFu + ((i >> 16) & 1u);
  return (u16)(r >> 16);
}
__device__ __forceinline__ float sigm(float x){ return 1.f/(1.f+__expf(-x)); }
__device__ __forceinline__ float wredsum(float v){
#pragma unroll
  for (int o=32;o>0;o>>=1) v += __shfl_xor(v,o);
  return v;
}
__device__ __forceinline__ void async16(const void* g, void* l){
  __builtin_amdgcn_global_load_lds(
      (const __attribute__((address_space(1))) unsigned int*)g,
      (__attribute__((address_space(3))) unsigned int*)l, 16, 0, 0);
}
__device__ __forceinline__ unsigned cvt_pk_bf16(float lo, float hi){
  unsigned r;
  asm("v_cvt_pk_bf16_f32 %0, %1, %2" : "=v"(r) : "v"(lo), "v"(hi));
  return r;
}
__device__ __forceinline__ void permlane32_swap(unsigned &a, unsigned &b){
  // after: a = {A[0:31], B[0:31]}, b = {A[32:63], B[32:63]}
  asm volatile("v_permlane32_swap_b32 %0, %1" : "+v"(a), "+v"(b));
}

// ---------------- 256x256 8-wave MFMA GEMM: C[M,N] = A[M,K] @ Bt[N,K]^T -----
// 8-phase schedule (verified r3/r4). epi==1: bf16 store. epi==2: gated
// atomicAdd (split-K safe). epi==3: interleaved gate/val -> silu(g)*v store
// to outB with N/2 cols (requires gridDim.z==1, Wgate columns interleaved).
__global__ __launch_bounds__(512) void gemm_bt(
    const u16* __restrict__ Ain, const u16* __restrict__ Bt,
    int M, int N, int K, int epi,
    u16* __restrict__ outB,
    float* __restrict__ dest, const float* __restrict__ gate)
{
  __shared__ u16 smem[2][2][2][8192];   // [slot][A=0/B=1][half][128x64], 128 KiB

  const int nwg  = gridDim.x * gridDim.y;
  const int orig = blockIdx.y * gridDim.x + blockIdx.x;
  const int qch  = nwg >> 3, rch = nwg & 7;
  const int xcd  = orig & 7, loc = orig >> 3;
  const int swzb = (xcd < rch ? xcd*(qch+1) : rch*(qch+1) + (xcd-rch)*qch) + loc;
  const int m0 = (swzb / gridDim.x) * 256;
  const int n0 = (swzb % gridDim.x) * 256;

  const int kchunk = K / gridDim.z;
  const int kbase  = blockIdx.z * kchunk;
  const int NT = kchunk >> 6;

  const int tid = threadIdx.x;
  const int w = tid >> 6, lane = tid & 63;
  const int quad = lane >> 4, l16 = lane & 15;
  const int wm = w >> 2, wn = w & 3;
  const int sx = (l16 & 7) << 4;

  int soff[2];
#pragma unroll
  for (int j=0;j<2;++j){
    const int row = (w*2 + j)*8 + (lane >> 3);
    soff[j] = row*(K*2) + (((lane & 7) ^ (row & 7)) << 4);
  }

  const char* pA0 = (const char*)(Ain + (size_t)m0*K       + kbase);
  const char* pA1 = (const char*)(Ain + (size_t)(m0+128)*K + kbase);
  const char* pB0 = (const char*)(Bt  + (size_t)n0*K       + kbase);
  const char* pB1 = (const char*)(Bt  + (size_t)(n0+128)*K + kbase);

  auto stage = [&](const char* base, int t, u16* region){
#pragma unroll
    for (int j=0;j<2;++j)
      async16(base + (size_t)t*128 + soff[j], (char*)region + (w*2+j)*1024);
  };

  f32x4 acc[8][4] = {};
  bf16x8 af[4][2];
  bf16x8 bq[4][2];

  stage(pA0, 0, &smem[0][0][0][0]);
  stage(pA1, 0, &smem[0][0][1][0]);
  stage(pB0, 0, &smem[0][1][0][0]);
  stage(pB1, 0, &smem[0][1][1][0]);
  if (NT > 1){
    stage(pA0, 1, &smem[1][0][0][0]);
    asm volatile("s_waitcnt vmcnt(2)" ::: "memory");
  } else {
    asm volatile("s_waitcnt vmcnt(0)" ::: "memory");
  }
  __builtin_amdgcn_s_barrier();

#pragma unroll 1
  for (int t=0; t<NT; ++t){
    const int s  = t & 1;
    const int s1 = s ^ 1;
    const char* Ah = (const char*)&smem[s][0][wm][0];
    const char* Bh = (const char*)&smem[s][1][wn>>1][0];
    const int bb = (wn & 1) * 64;

    // P1
#pragma unroll
    for (int mf=0; mf<4; ++mf)
#pragma unroll
      for (int ks=0; ks<2; ++ks){
        const int b = ((mf*16 + l16)*128 + ks*64 + quad*16) ^ sx;
        af[mf][ks] = *reinterpret_cast<const bf16x8*>(Ah + b);
      }
#pragma unroll
    for (int nf=0; nf<2; ++nf)
#pragma unroll
      for (int ks=0; ks<2; ++ks){
        const int b = ((bb + nf*16 + l16)*128 + ks*64 + quad*16) ^ sx;
        bq[nf][ks] = *reinterpret_cast<const bf16x8*>(Bh + b);
      }
    if (t+1 < NT) stage(pA1, t+1, &smem[s1][0][1][0]);
    __builtin_amdgcn_sched_barrier(0);
    __builtin_amdgcn_s_barrier();
    asm volatile("s_waitcnt lgkmcnt(0)" ::: "memory");
    __builtin_amdgcn_sched_barrier(0);
    __builtin_amdgcn_s_setprio(1);
#pragma unroll
    for (int mf=0; mf<4; ++mf)
#pragma unroll
      for (int nf=0; nf<2; ++nf)
#pragma unroll
        for (int ks=0; ks<2; ++ks)
          acc[mf][nf] = __builtin_amdgcn_mfma_f32_16x16x32_bf16(af[mf][ks], bq[nf][ks], acc[mf][nf], 0,0,0);
    __builtin_amdgcn_s_setprio(0);
    __builtin_amdgcn_sched_barrier(0);
    __builtin_amdgcn_s_barrier();

    // P2
#pragma unroll
    for (int nf=0; nf<2; ++nf)
#pragma unroll
      for (int ks=0; ks<2; ++ks){
        const int b = ((bb + (2+nf)*16 + l16)*128 + ks*64 + quad*16) ^ sx;
        bq[2+nf][ks] = *reinterpret_cast<const bf16x8*>(Bh + b);
      }
    if (t+1 < NT) stage(pB0, t+1, &smem[s1][1][0][0]);
    __builtin_amdgcn_sched_barrier(0);
    __builtin_amdgcn_s_barrier();
    asm volatile("s_waitcnt lgkmcnt(0)" ::: "memory");
    __builtin_amdgcn_sched_barrier(0);
    __builtin_amdgcn_s_setprio(1);
#pragma unroll
    for (int mf=0; mf<4; ++mf)
#pragma unroll
      for (int nf=0; nf<2; ++nf)
#pragma unroll
        for (int ks=0; ks<2; ++ks)
          acc[mf][2+nf] = __builtin_amdgcn_mfma_f32_16x16x32_bf16(af[mf][ks], bq[2+nf][ks], acc[mf][2+nf], 0,0,0);
    __builtin_amdgcn_s_setprio(0);
    __builtin_amdgcn_sched_barrier(0);
    __builtin_amdgcn_s_barrier();

    // P3
#pragma unroll
    for (int mf=0; mf<4; ++mf)
#pragma unroll
      for (int ks=0; ks<2; ++ks){
        const int b = ((64 + mf*16 + l16)*128 + ks*64 + quad*16) ^ sx;
        af[mf][ks] = *reinterpret_cast<const bf16x8*>(Ah + b);
      }
    if (t+1 < NT) stage(pB1, t+1, &smem[s1][1][1][0]);
    __builtin_amdgcn_sched_barrier(0);
    __builtin_amdgcn_s_barrier();
    asm volatile("s_waitcnt lgkmcnt(0)" ::: "memory");
    __builtin_amdgcn_sched_barrier(0);
    __builtin_amdgcn_s_setprio(1);
#pragma unroll
    for (int mf=0; mf<4; ++mf)
#pragma unroll
      for (int nf=0; nf<2; ++nf)
#pragma unroll
        for (int ks=0; ks<2; ++ks)
          acc[4+mf][2+nf] = __builtin_amdgcn_mfma_f32_16x16x32_bf16(af[mf][ks], bq[2+nf][ks], acc[4+mf][2+nf], 0,0,0);
    __builtin_amdgcn_s_setprio(0);
    __builtin_amdgcn_sched_barrier(0);
    __builtin_amdgcn_s_barrier();

    // P4
    if (t+2 < NT) stage(pA0, t+2, &smem[s][0][0][0]);
    __builtin_amdgcn_sched_barrier(0);
    __builtin_amdgcn_s_barrier();
    __builtin_amdgcn_s_setprio(1);
#pragma unroll
    for (int mf=0; mf<4; ++mf)
#pragma unroll
      for (int nf=0; nf<2; ++nf)
#pragma unroll
        for (int ks=0; ks<2; ++ks)
          acc[4+mf][nf] = __builtin_amdgcn_mfma_f32_16x16x32_bf16(af[mf][ks], bq[nf][ks], acc[4+mf][nf], 0,0,0);
    __builtin_amdgcn_s_setprio(0);
    __builtin_amdgcn_sched_barrier(0);
    if (t+2 < NT) asm volatile("s_waitcnt vmcnt(2)" ::: "memory");
    else          asm volatile("s_waitcnt vmcnt(0)" ::: "memory");
    __builtin_amdgcn_s_barrier();
  }

#pragma unroll
  for (int i=0;i<8;++i){
    const int row = m0 + wm*128 + (i>>2)*64 + (i&3)*16 + quad*4;
#pragma unroll
    for (int j=0;j<4;++j){
      const int col = n0 + wn*64 + j*16 + l16;
#pragma unroll
      for (int r=0;r<4;++r){
        const float v = acc[i][j][r];
        const size_t idx = (size_t)(row + r)*N + col;
        if (epi==1){ outB[idx] = f2b(v); }
        else if (epi==3){
          const float pv2 = __shfl_xor(v, 1);     // partner col (val for even lanes)
          if ((l16 & 1) == 0){
            const float o = v*sigm(v)*pv2;        // silu(gate)*val
            outB[(size_t)(row + r)*(N>>1) + (col>>1)] = f2b(o);
          }
        } else {
          const int b = (row + r) >> 11;
          atomicAdd(&dest[idx], gate[b*MODS_STRIDE + col] * v);
        }
      }
    }
  }
}

// -------- batched transpose+convert: dst[n'*dstride+doff+r] = f2b(src[r*cols+n])
// ileave!=0: n' = (n<ileave)? 2n : 2(n-ileave)+1  (gate/val column interleave)
struct TDesc { const float* src; u16* dst; int rows; int cols; int base; int dstride; int doff; int ileave; };
struct TPack { TDesc d[16]; };

__global__ __launch_bounds__(256) void transpose_all(TPack p, int nmat)
{
  __shared__ float t[32][33];
  const int bid = blockIdx.x;
  int mi = 0;
#pragma unroll 1
  while (mi+1 < nmat && bid >= p.d[mi+1].base) ++mi;
  const TDesc D = p.d[mi];
  const int tid2   = bid - D.base;
  const int tilesx = D.cols >> 5;
  const int r0 = (tid2 / tilesx) * 32;
  const int c0 = (tid2 % tilesx) * 32;
  const int tx = threadIdx.x & 31, ty = threadIdx.x >> 5;
  for (int i=ty;i<32;i+=8)
    t[i][tx] = D.src[(size_t)(r0+i)*D.cols + c0 + tx];
  __syncthreads();
  for (int i=ty;i<32;i+=8){
    int n = c0 + i;
    if (D.ileave) n = (n < D.ileave) ? 2*n : 2*(n - D.ileave) + 1;
    D.dst[(size_t)n*D.dstride + D.doff + r0 + tx] = f2b(t[tx][i]);
  }
}

// ---- LoRA fold: WqkvT[n][k] += mag[n>>6] * sum_r la[k][r]*lb[r][n]  (n<1024)
__global__ __launch_bounds__(256) void lora_fold(
    const float* __restrict__ la, const float* __restrict__ lb,
    const float* __restrict__ mag, u16* __restrict__ WqkvT)
{
  const unsigned idx = blockIdx.x*256u + threadIdx.x;   // 1M
  const int k = idx & 1023, n = idx >> 10;
  float s = 0.f;
#pragma unroll
  for (int r=0;r<16;++r)
    s = fmaf(la[k*16+r], lb[r*1024+n], s);
  const float m = mag[n>>6];
  const unsigned o = (unsigned)n*1024u + k;
  WqkvT[o] = f2b(b2f(WqkvT[o]) + m*s);
}

// ---------------- LayerNorm (+ optional modulate, + optional residual copy) ---
__global__ __launch_bounds__(256) void ln_kernel(
    const float* __restrict__ xin,
    const float* __restrict__ w, const float* __restrict__ bias,
    const float* __restrict__ mods, int sh_off, int sc_off,
    u16* __restrict__ out_norm, u16* __restrict__ out_mod,
    float* __restrict__ out_xw)
{
  const int row = blockIdx.x;
  const int b = row >> 11;
  const int t = threadIdx.x;
  float v[4];
#pragma unroll
  for (int e=0;e<4;++e)
    v[e] = xin[(size_t)row*CDIM + t*4+e];
  float s  = v[0]+v[1]+v[2]+v[3];
  float ss = v[0]*v[0]+v[1]*v[1]+v[2]*v[2]+v[3]*v[3];
  s = wredsum(s); ss = wredsum(ss);
  __shared__ float rs[4], rss[4];
  const int wv = t>>6;
  if ((t&63)==0){ rs[wv]=s; rss[wv]=ss; }
  __syncthreads();
  s  = rs[0]+rs[1]+rs[2]+rs[3];
  ss = rss[0]+rss[1]+rss[2]+rss[3];
  const float mean = s * (1.f/1024.f);
  const float var  = ss * (1.f/1024.f) - mean*mean;
  const float rinv = rsqrtf(var + 1e-5f);
#pragma unroll
  for (int e=0;e<4;++e){
    const int c = t*4+e;
    const float nv = (v[e]-mean)*rinv*w[c] + bias[c];
    if (out_norm) out_norm[(size_t)row*CDIM+c] = f2b(nv);
    if (out_mod){
      const float sc = mods[b*MODS_STRIDE + sc_off + c];
      const float sh = mods[b*MODS_STRIDE + sh_off + c];
      out_mod[(size_t)row*CDIM+c] = f2b(nv*(1.f+sc)+sh);
    }
    if (out_xw) out_xw[(size_t)row*CDIM+c] = v[e];
  }
}

// ---------------- adaLN ------------------------------------------------------
__global__ __launch_bounds__(256) void ada_init(
    const float* __restrict__ ab, float* __restrict__ mods)
{
  const int j = blockIdx.x*256 + threadIdx.x;     // < 12288
  const int jj = (j >= MODS_STRIDE) ? j - MODS_STRIDE : j;
  mods[j] = ab[jj];
}

__global__ __launch_bounds__(256) void ada_split(
    const float* __restrict__ cin, const float* __restrict__ aw,
    float* __restrict__ mods)
{
  const int j  = blockIdx.x*256 + threadIdx.x;    // 0..6143
  const int k0 = blockIdx.y*64;
  float s0 = 0.f, s1 = 0.f;
  for (int k=k0; k<k0+64; ++k){
    const float wv = aw[(size_t)k*MODS_STRIDE + j];
    const float c0 = cin[k], c1 = cin[CDIM + k];
    s0 = fmaf(c0*sigm(c0), wv, s0);
    s1 = fmaf(c1*sigm(c1), wv, s1);
  }
  atomicAdd(&mods[j], s0);
  atomicAdd(&mods[MODS_STRIDE + j], s1);
}

// ---------------- MFMA flash attention, 32x32 MFMA + in-register P (T12) -----
// 4 waves x 32 queries = 128 q/block; K/V staged once per 64-key tile; P never
// touches LDS (cvt_pk_bf16 + permlane32_swap redistribute the half-rows).
// Lane layout (32x32x16): A row / B col = lane&31; k = (lane>>5)*8+j.
// C: col=lane&31, row=(reg&3)+8*(reg>>2)+4*(lane>>5)  [m74/m101].
__global__ __launch_bounds__(256) void attn_mfma(
    const u16* __restrict__ qkv, u16* __restrict__ AH)
{
  __shared__ u16 Kl[64*64];       // [key][64d] swizzled, 8KB
  __shared__ u16 Vt[64*64];       // [d][64key] swizzled, 8KB
  const int t = threadIdx.x;
  const int w = t>>6, lane = t&63;
  const int l32 = lane & 31, hi = lane >> 5;
  const int qt = blockIdx.x, h = blockIdx.y, b = blockIdx.z;
  const size_t rowbase = (size_t)b*NTOK;

  // ---- Q fragments: qf[dstep] = Q[q=l32][dstep*16 + hi*8 + 0..7] * 0.125 ----
  bf16x8 qf[4];
  {
    const size_t gr = rowbase + qt*128 + w*32 + l32;
    const u16* qp = qkv + gr*3072 + h*64;
#pragma unroll
    for (int ds=0; ds<4; ++ds){
      const u16x8 qa = *reinterpret_cast<const u16x8*>(qp + ds*16 + hi*8);
#pragma unroll
      for (int j=0;j<8;++j)
        qf[ds][j] = (__bf16)(b2f(qa[j]) * 0.125f);
    }
  }

  // ---- staging sources + swizzled LDS write offsets ----
  const u16* ksrc[2]; int kwr[2];
#pragma unroll
  for (int it=0; it<2; ++it){
    const int e = it*256 + t;
    const int key = e>>3, ch = e&7;
    ksrc[it] = qkv + (rowbase + key)*3072 + 1024 + h*64 + ch*8;
    kwr[it]  = key*128 + ((ch ^ (key&7)) << 4);
  }
  const u16* vsrc[2]; int vwr[2][8];
#pragma unroll
  for (int it=0; it<2; ++it){
    const int d0 = (w*2 + it)*8;
    vsrc[it] = qkv + (rowbase + lane)*3072 + 2048 + h*64 + d0;
#pragma unroll
    for (int j=0;j<8;++j){
      const int d = d0 + j;
      vwr[it][j] = d*128 + (((lane>>3) ^ (d&7)) << 4) + (lane&7)*2;
    }
  }
  // K read offsets: row key = st*32+l32, chunk = ds*2+hi
  int kra[2][4];
#pragma unroll
  for (int st=0; st<2; ++st)
#pragma unroll
    for (int ds=0; ds<4; ++ds){
      const int key = st*32 + l32;
      kra[st][ds] = key*128 + (((ds*2 + hi) ^ (key&7)) << 4);
    }
  // V read offsets: row d = dt*32+l32, chunk = st*4+ks*2+hi
  int vra[2][2][2];
#pragma unroll
  for (int st=0; st<2; ++st)
#pragma unroll
    for (int ks=0; ks<2; ++ks)
#pragma unroll
      for (int dt=0; dt<2; ++dt){
        const int d = dt*32 + l32;
        vra[st][ks][dt] = d*128 + (((st*4 + ks*2 + hi) ^ (d&7)) << 4);
      }

  const size_t KSTRIDE = (size_t)64*3072;

  u16x8 kA[2], vA[2], kB[2], vB[2];
#pragma unroll
  for (int it=0; it<2; ++it){
    kA[it] = *reinterpret_cast<const u16x8*>(ksrc[it]);
    vA[it] = *reinterpret_cast<const u16x8*>(vsrc[it]);
  }

  float l_part = 0.f;
  f32x16 oacc[2] = {};   // [dtile]; O[d=dt*32+l32][q rows crow(r,hi)]

  auto step = [&](u16x8 (&kk)[2], u16x8 (&vv)[2], int kbn,
                  u16x8 (&kn)[2], u16x8 (&vn)[2]){
#pragma unroll
    for (int it=0; it<2; ++it){
      *reinterpret_cast<u16x8*>((char*)Kl + kwr[it]) = kk[it];
#pragma unroll
      for (int j=0;j<8;++j)
        *reinterpret_cast<u16*>((char*)Vt + vwr[it][j]) = vv[it][j];
    }
    __syncthreads();
    {
      const size_t off = (size_t)kbn * KSTRIDE;
#pragma unroll
      for (int it=0; it<2; ++it){
        kn[it] = *reinterpret_cast<const u16x8*>(ksrc[it] + off);
        vn[it] = *reinterpret_cast<const u16x8*>(vsrc[it] + off);
      }
    }
    // QK^T: sacc[st] = S[key=crow(r,hi)+st*32][q=l32]
    f32x16 sacc[2] = {};
#pragma unroll
    for (int st=0; st<2; ++st)
#pragma unroll
      for (int ds=0; ds<4; ++ds){
        const bf16x8 af = *reinterpret_cast<const bf16x8*>((char*)Kl + kra[st][ds]);
        sacc[st] = __builtin_amdgcn_mfma_f32_32x32x16_bf16(af, qf[ds], sacc[st], 0,0,0);
      }
    // exp + partial row-sum (this lane covers half the keys of query l32)
#pragma unroll
    for (int st=0; st<2; ++st)
#pragma unroll
      for (int r=0;r<16;++r){
        const float pv = __expf(sacc[st][r]);
        sacc[st][r] = pv;
        l_part += pv;
      }
    // P -> registers: per subtile, 8 cvt_pk + 4 permlane swaps -> pa[2 ksteps]
#pragma unroll
    for (int st=0; st<2; ++st){
      unsigned wd[8];
#pragma unroll
      for (int m=0;m<8;++m)
        wd[m] = cvt_pk_bf16(sacc[st][2*m], sacc[st][2*m+1]);
      permlane32_swap(wd[0], wd[2]);
      permlane32_swap(wd[1], wd[3]);
      permlane32_swap(wd[4], wd[6]);
      permlane32_swap(wd[5], wd[7]);
      u32x4 paw[2];
      paw[0] = u32x4{wd[0], wd[1], wd[2], wd[3]};
      paw[1] = u32x4{wd[4], wd[5], wd[6], wd[7]};
#pragma unroll
      for (int ks=0; ks<2; ++ks){
        const bf16x8 pa = *reinterpret_cast<const bf16x8*>(&paw[ks]);
#pragma unroll
        for (int dt=0; dt<2; ++dt){
          const bf16x8 vb = *reinterpret_cast<const bf16x8*>((char*)Vt + vra[st][ks][dt]);
          oacc[dt] = __builtin_amdgcn_mfma_f32_32x32x16_bf16(pa, vb, oacc[dt], 0,0,0);
        }
      }
    }
    __syncthreads();
  };

#pragma unroll 1
  for (int kb=0; kb<32; kb+=2){
    step(kA, vA, (kb+1 < 32 ? kb+1 : 31), kB, vB);
    step(kB, vB, (kb+2 < 32 ? kb+2 : 31), kA, vA);
  }

  // l[q=l32] = own half + partner half (lane^32 has same q)
  const float l_run = l_part + __shfl_xor(l_part, 32);

  // output: O[q=crow(r,hi)][d=dt*32+l32], normalize by l[crow]
#pragma unroll
  for (int r=0;r<16;++r){
    const int crow = (r&3) + 8*(r>>2) + 4*hi;
    const float li = __shfl(l_run, crow);
    const size_t grow = rowbase + qt*128 + w*32 + crow;
#pragma unroll
    for (int dt=0; dt<2; ++dt)
      AH[grow*2048 + h*64 + dt*32 + l32] = f2b(oacc[dt][r] / li);
  }
}

// ---------------- HGRN chunked scan (32 chunks of 64) --------------------------
__global__ __launch_bounds__(256) void scan_p1(
    const u16* __restrict__ FIG, float* __restrict__ cA, float* __restrict__ cH)
{
  const unsigned int idx = blockIdx.x*256u + threadIdx.x;
  const unsigned int c = idx & 1023u, chunk = (idx>>10)&(NCHUNK-1), b = idx>>15;
  float A = 1.f, h = 0.f;
  const size_t base = ((size_t)b*NTOK + chunk*CHLEN) * 3072;
  for (int t=0;t<CHLEN;++t){
    const float F = b2f(FIG[base + (size_t)t*3072 + c]);
    const float I = b2f(FIG[base + (size_t)t*3072 + 1024 + c]);
    const float f = sigm(F);
    const float il = I*sigm(I) * (1.f - f);
    A *= f;
    h = fmaf(f, h, il);
  }
  cA[idx] = A; cH[idx] = h;
}

__global__ __launch_bounds__(256) void scan_p2(
    const float* __restrict__ cA, const float* __restrict__ cH, float* __restrict__ Hinit)
{
  const unsigned int idx = blockIdx.x*256u + threadIdx.x;  // [0,2048)
  const unsigned int b = idx>>10, c = idx&1023u;
  float h = 0.f;
#pragma unroll
  for (int ch=0;ch<NCHUNK;++ch){
    const unsigned int q = (b*NCHUNK + ch)*1024 + c;
    Hinit[q] = h;
    h = fmaf(cA[q], h, cH[q]);
  }
}

__global__ __launch_bounds__(256) void scan_p3(
    const u16* __restrict__ FIG, const float* __restrict__ Hinit, u16* __restrict__ Hb)
{
  const unsigned int idx = blockIdx.x*256u + threadIdx.x;
  const unsigned int c = idx & 1023u, chunk = (idx>>10)&(NCHUNK-1), b = idx>>15;
  float h = Hinit[idx];
  const size_t base = ((size_t)b*NTOK + chunk*CHLEN) * 3072;
  const size_t obase = ((size_t)b*NTOK + chunk*CHLEN) * CDIM;
  for (int t=0;t<CHLEN;++t){
    const float F = b2f(FIG[base + (size_t)t*3072 + c]);
    const float I = b2f(FIG[base + (size_t)t*3072 + 1024 + c]);
    const float f = sigm(F);
    const float il = I*sigm(I) * (1.f - f);
    h = fmaf(f, h, il);
    Hb[obase + (size_t)t*CDIM + c] = f2b(h);
  }
}

// ---------------- HGRN post: per-head RMSNorm * gn * silu(G) -------------------
__global__ __launch_bounds__(256) void hgrn_post(
    const u16* __restrict__ Hb, const u16* __restrict__ FIG,
    const float* __restrict__ gn, u16* __restrict__ AH)
{
  const int row = blockIdx.x;
  const int t = threadIdx.x;
  float hv[4]; float ss = 0.f;
#pragma unroll
  for (int e=0;e<4;++e){
    hv[e] = b2f(Hb[(size_t)row*CDIM + t*4 + e]);
    ss = fmaf(hv[e], hv[e], ss);
  }
#pragma unroll
  for (int o=1;o<16;o<<=1) ss += __shfl_xor(ss, o);
  const float rinv = rsqrtf(ss*(1.f/64.f) + 1e-5f);
#pragma unroll
  for (int e=0;e<4;++e){
    const int c = t*4+e;
    const float g = b2f(FIG[(size_t)row*3072 + 2048 + c]);
    AH[(size_t)row*2048 + 1024 + c] = f2b(hv[e]*rinv*gn[c] * g*sigm(g));
  }
}

__global__ __launch_bounds__(256) void store_out(
    const float* __restrict__ xw, float* __restrict__ out)
{
  const unsigned int i = blockIdx.x*256u + threadIdx.x;
  out[i] = xw[i];
}

__global__ __launch_bounds__(256) void fill_fail(float* __restrict__ out)
{
  const unsigned int i = blockIdx.x*256u + threadIdx.x;
  out[i] = 1234.5f;
}

// ---------------- host orchestration ------------------------------------------
static void run_stream(hipStream_t stream,
    const float* Xin, const float* LNW, const float* LNB,
    const float* MAG, const float* LA, const float* LBw, const float* GN,
    float* mods, float* xw, float* outp,
    u16* WqkvT, const u16* WpwT, const u16* WhgrnT,
    const u16* WgateT, const u16* WdownT,
    u16* x_norm, u16* v_h, u16* qkvb, u16* delta, u16* AH,
    float* cA, float* cH, float* Hinit, u16* actb)
{
  u16* FIG    = qkvb;
  u16* Hb     = delta;
  u16* mlp_in = x_norm;

  lora_fold<<<4096,256,0,stream>>>(LA, LBw, MAG, WqkvT);

  ln_kernel<<<ROWS,256,0,stream>>>(Xin, LNW, LNB, mods, 0, 1024, x_norm, v_h, xw);

  // attention branch -> AH[:,0:1024]
  gemm_bt<<<dim3(12,16),512,0,stream>>>(x_norm, WqkvT, ROWS,3072,1024, 1, qkvb, nullptr, nullptr);
  attn_mfma<<<dim3(16,16,2),256,0,stream>>>(qkvb, AH);

  // HGRN branch -> AH[:,1024:2048]
  gemm_bt<<<dim3(12,16),512,0,stream>>>(v_h, WhgrnT, ROWS,3072,1024, 1, FIG, nullptr, nullptr);
  scan_p1<<<2*NCHUNK*1024/256,256,0,stream>>>(FIG, cA, cH);
  scan_p2<<<8,256,0,stream>>>(cA, cH, Hinit);
  scan_p3<<<2*NCHUNK*1024/256,256,0,stream>>>(FIG, Hinit, Hb);
  hgrn_post<<<ROWS,256,0,stream>>>(Hb, FIG, GN, AH);

  // fused proj+wo: xw += g_msa * (AH @ [Wproj;Wwo]^T), split-K=4
  gemm_bt<<<dim3(4,16,4),512,0,stream>>>(AH, WpwT, ROWS,1024,2048, 2, nullptr, xw, mods+2048);

  // MLP: gate GEMM with fused silu(g)*v epilogue (interleaved Wgate cols)
  ln_kernel<<<ROWS,256,0,stream>>>(xw, LNW, LNB, mods, 3072, 4096, nullptr, mlp_in, nullptr);
  gemm_bt<<<dim3(22,16),512,0,stream>>>(mlp_in, WgateT, ROWS,5632,1024, 3, actb, nullptr, nullptr);
  // down-proj split-K=4: xw += g_mlp * (act @ Wdown^T)
  gemm_bt<<<dim3(4,16,4),512,0,stream>>>(actb, WdownT, ROWS,1024,2816, 2, nullptr, xw, mods+5120);

  store_out<<<ROWS*CDIM/256,256,0,stream>>>(xw, outp);
}

extern "C" void kernel_launch(void* const* d_in, const int* in_sizes, int n_in,
                              void* d_out, int out_size, void* d_ws, size_t ws_size,
                              hipStream_t stream)
{
  const float* X    = (const float*)d_in[0];
  const float* Y    = (const float*)d_in[1];
  const float* Cc   = (const float*)d_in[2];
  const float* GXW  = (const float*)d_in[3];
  const float* GXB  = (const float*)d_in[4];
  const float* GYW  = (const float*)d_in[5];
  const float* GYB  = (const float*)d_in[6];
  const float* ADAW = (const float*)d_in[7];
  const float* ADAB = (const float*)d_in[8];
  const float* XY_QKV = (const float*)d_in[9];
  const float* XY_MAG = (const float*)d_in[10];
  const float* XY_LA  = (const float*)d_in[11];
  const float* XY_LB  = (const float*)d_in[12];
  const float* XY_PROJ= (const float*)d_in[13];
  const float* YX_QKV = (const float*)d_in[14];
  const float* YX_MAG = (const float*)d_in[15];
  const float* YX_LA  = (const float*)d_in[16];
  const float* YX_LB  = (const float*)d_in[17];
  const float* YX_PROJ= (const float*)d_in[18];
  const float* AX_WI = (const float*)d_in[19];
  const float* AX_WF = (const float*)d_in[20];
  const float* AX_WG = (const float*)d_in[21];
  const float* AX_WO = (const float*)d_in[22];
  const float* AX_GN = (const float*)d_in[23];
  const float* AY_WI = (const float*)d_in[24];
  const float* AY_WF = (const float*)d_in[25];
  const float* AY_WG = (const float*)d_in[26];
  const float* AY_WO = (const float*)d_in[27];
  const float* AY_GN = (const float*)d_in[28];
  const float* MX_GATE = (const float*)d_in[29];
  const float* MX_DOWN = (const float*)d_in[30];
  const float* MY_GATE = (const float*)d_in[31];
  const float* MY_DOWN = (const float*)d_in[32];
  float* OUT = (float*)d_out;

  char* p = (char*)d_ws;
  size_t off = 0;
  auto alloc = [&](size_t bytes)->char*{
    char* r = p + off;
    off = (off + bytes + 255) & ~(size_t)255;
    return r;
  };
  float* mods  = (float*)alloc(2*MODS_STRIDE*sizeof(float));
  float* xw_x  = (float*)alloc((size_t)ROWS*CDIM*sizeof(float));
  float* xw_y  = (float*)alloc((size_t)ROWS*CDIM*sizeof(float));
  u16* WqkvT0  = (u16*)alloc((size_t)3072*1024*2);
  u16* WqkvT1  = (u16*)alloc((size_t)3072*1024*2);
  u16* WpwT0   = (u16*)alloc((size_t)1024*2048*2);
  u16* WpwT1   = (u16*)alloc((size_t)1024*2048*2);
  u16* WhgrnT0 = (u16*)alloc((size_t)3072*1024*2);
  u16* WhgrnT1 = (u16*)alloc((size_t)3072*1024*2);
  u16* WgateT0 = (u16*)alloc((size_t)5632*1024*2);
  u16* WgateT1 = (u16*)alloc((size_t)5632*1024*2);
  u16* WdownT0 = (u16*)alloc((size_t)1024*2816*2);
  u16* WdownT1 = (u16*)alloc((size_t)1024*2816*2);
  u16* x_norm  = (u16*)alloc((size_t)ROWS*CDIM*2);
  u16* v_h     = (u16*)alloc((size_t)ROWS*CDIM*2);
  u16* qkvb    = (u16*)alloc((size_t)ROWS*3072*2);
  u16* delta   = (u16*)alloc((size_t)ROWS*CDIM*2);
  u16* AH      = (u16*)alloc((size_t)ROWS*2048*2);
  float* cA    = (float*)alloc((size_t)2*NCHUNK*1024*sizeof(float));
  float* cH    = (float*)alloc((size_t)2*NCHUNK*1024*sizeof(float));
  float* Hinit = (float*)alloc((size_t)2*NCHUNK*1024*sizeof(float));
  u16* actb    = (u16*)alloc((size_t)ROWS*INTERDIM*2);

  if (off > ws_size){
    fill_fail<<<(2*ROWS*CDIM)/256,256,0,stream>>>(OUT);
    return;
  }

  ada_init<<<2*MODS_STRIDE/256,256,0,stream>>>(ADAB, mods);
  ada_split<<<dim3(MODS_STRIDE/256,16),256,0,stream>>>(Cc, ADAW, mods);

  TPack tp; int base = 0; int ndesc = 0;
  auto add = [&](const float* s, u16* d2, int rows, int cols, int dstride, int doff, int il){
    tp.d[ndesc].src = s; tp.d[ndesc].dst = d2;
    tp.d[ndesc].rows = rows; tp.d[ndesc].cols = cols; tp.d[ndesc].base = base;
    tp.d[ndesc].dstride = dstride; tp.d[ndesc].doff = doff; tp.d[ndesc].ileave = il;
    base += (rows>>5)*(cols>>5); ++ndesc;
  };
  add(XY_QKV,  WqkvT0, 1024, 3072, 1024, 0, 0);
  add(XY_PROJ, WpwT0,  1024, 1024, 2048, 0, 0);
  add(AX_WO,   WpwT0,  1024, 1024, 2048, 1024, 0);
  add(AX_WF, WhgrnT0,               1024, 1024, 1024, 0, 0);
  add(AX_WI, WhgrnT0 + 1024*1024,   1024, 1024, 1024, 0, 0);
  add(AX_WG, WhgrnT0 + 2*1024*1024, 1024, 1024, 1024, 0, 0);
  add(MX_GATE, WgateT0, 1024, 5632, 1024, 0, INTERDIM);
  add(MX_DOWN, WdownT0, 2816, 1024, 2816, 0, 0);
  add(YX_QKV,  WqkvT1, 1024, 3072, 1024, 0, 0);
  add(YX_PROJ, WpwT1,  1024, 1024, 2048, 0, 0);
  add(AY_WO,   WpwT1,  1024, 1024, 2048, 1024, 0);
  add(AY_WF, WhgrnT1,               1024, 1024, 1024, 0, 0);
  add(AY_WI, WhgrnT1 + 1024*1024,   1024, 1024, 1024, 0, 0);
  add(AY_WG, WhgrnT1 + 2*1024*1024, 1024, 1024, 1024, 0, 0);
  add(MY_GATE, WgateT1, 1024, 5632, 1024, 0, INTERDIM);
  add(MY_DOWN, WdownT1, 2816, 1024, 2816, 0, 0);
  transpose_all<<<base,256,0,stream>>>(tp, ndesc);

  run_stream(stream, X, GXW, GXB, XY_MAG, XY_LA, XY_LB, AX_GN,
             mods, xw_x, OUT,
             WqkvT0, WpwT0, WhgrnT0, WgateT0, WdownT0,
             x_norm, v_h, qkvb, delta, AH,
             cA, cH, Hinit, actb);

  run_stream(stream, Y, GYW, GYB, YX_MAG, YX_LA, YX_LB, AY_GN,
             mods, xw_y, OUT + (size_t)ROWS*CDIM,
             WqkvT1, WpwT1, WhgrnT1, WgateT1, WdownT1,
             x_norm, v_h, qkvb, delta, AH,
             cA, cH, Hinit, actb);
}

// Round 13
// 1216.998 us; speedup vs baseline: 1.0494x; 1.0494x over previous
//
#include <hip/hip_runtime.h>
#include <stdint.h>

#define NTOK 2048
#define CDIM 1024
#define ROWS 4096          // B*N
#define MODS_STRIDE 6144
#define INTERDIM 2816
#define NCHUNK 32
#define CHLEN (NTOK/NCHUNK)   // 64

typedef unsigned short u16;
typedef __bf16 bf16x8 __attribute__((ext_vector_type(8)));
typedef float f32x4 __attribute__((ext_vector_type(4)));
typedef float f32x16 __attribute__((ext_vector_type(16)));
typedef u16 u16x8 __attribute__((ext_vector_type(8)));
typedef unsigned int u32x4 __attribute__((ext_vector_type(4)));

__device__ __forceinline__ float b2f(u16 u){
  union { unsigned int i; float f; } v; v.i = ((unsigned int)u) << 16; return v.f;
}
__device__ __forceinline__ u16 f2b(float f){
  union { float f; unsigned int i; } v; v.f = f;
  unsigned int i = v.i;
  unsigned int r = i + 0x7FFFu + ((i >> 16) & 1u);
  return (u16)(r >> 16);
}
__device__ __forceinline__ float sigm(float x){ return 1.f/(1.f+__expf(-x)); }
__device__ __forceinline__ float wredsum(float v){
#pragma unroll
  for (int o=32;o>0;o>>=1) v += __shfl_xor(v,o);
  return v;
}
__device__ __forceinline__ void async16(const void* g, void* l){
  __builtin_amdgcn_global_load_lds(
      (const __attribute__((address_space(1))) unsigned int*)g,
      (__attribute__((address_space(3))) unsigned int*)l, 16, 0, 0);
}
__device__ __forceinline__ unsigned cvt_pk_bf16(float lo, float hi){
  unsigned r;
  asm("v_cvt_pk_bf16_f32 %0, %1, %2" : "=v"(r) : "v"(lo), "v"(hi));
  return r;
}
__device__ __forceinline__ void permlane32_swap(unsigned &a, unsigned &b){
  // after: a = {A[0:31], B[0:31]}, b = {A[32:63], B[32:63]}
  asm volatile("v_permlane32_swap_b32 %0, %1" : "+v"(a), "+v"(b));
}

// ---------------- 256x256 8-wave MFMA GEMM: C[M,N] = A[M,K] @ Bt[N,K]^T -----
// 8-phase schedule, epilogue reverted to the round-4-verified two-branch form
// (epi==3 fused activation REMOVED — it doubled the gate GEMM, r11 post-mortem).
// epi==1: store bf16 to outB (gridDim.z==1). epi==2: gated atomicAdd.
__global__ __launch_bounds__(512) void gemm_bt(
    const u16* __restrict__ Ain, const u16* __restrict__ Bt,
    int M, int N, int K, int epi,
    u16* __restrict__ outB,
    float* __restrict__ dest, const float* __restrict__ gate)
{
  __shared__ u16 smem[2][2][2][8192];   // [slot][A=0/B=1][half][128x64], 128 KiB

  const int nwg  = gridDim.x * gridDim.y;
  const int orig = blockIdx.y * gridDim.x + blockIdx.x;
  const int qch  = nwg >> 3, rch = nwg & 7;
  const int xcd  = orig & 7, loc = orig >> 3;
  const int swzb = (xcd < rch ? xcd*(qch+1) : rch*(qch+1) + (xcd-rch)*qch) + loc;
  const int m0 = (swzb / gridDim.x) * 256;
  const int n0 = (swzb % gridDim.x) * 256;

  const int kchunk = K / gridDim.z;
  const int kbase  = blockIdx.z * kchunk;
  const int NT = kchunk >> 6;

  const int tid = threadIdx.x;
  const int w = tid >> 6, lane = tid & 63;
  const int quad = lane >> 4, l16 = lane & 15;
  const int wm = w >> 2, wn = w & 3;
  const int sx = (l16 & 7) << 4;

  int soff[2];
#pragma unroll
  for (int j=0;j<2;++j){
    const int row = (w*2 + j)*8 + (lane >> 3);
    soff[j] = row*(K*2) + (((lane & 7) ^ (row & 7)) << 4);
  }

  const char* pA0 = (const char*)(Ain + (size_t)m0*K       + kbase);
  const char* pA1 = (const char*)(Ain + (size_t)(m0+128)*K + kbase);
  const char* pB0 = (const char*)(Bt  + (size_t)n0*K       + kbase);
  const char* pB1 = (const char*)(Bt  + (size_t)(n0+128)*K + kbase);

  auto stage = [&](const char* base, int t, u16* region){
#pragma unroll
    for (int j=0;j<2;++j)
      async16(base + (size_t)t*128 + soff[j], (char*)region + (w*2+j)*1024);
  };

  f32x4 acc[8][4] = {};
  bf16x8 af[4][2];
  bf16x8 bq[4][2];

  stage(pA0, 0, &smem[0][0][0][0]);
  stage(pA1, 0, &smem[0][0][1][0]);
  stage(pB0, 0, &smem[0][1][0][0]);
  stage(pB1, 0, &smem[0][1][1][0]);
  if (NT > 1){
    stage(pA0, 1, &smem[1][0][0][0]);
    asm volatile("s_waitcnt vmcnt(2)" ::: "memory");
  } else {
    asm volatile("s_waitcnt vmcnt(0)" ::: "memory");
  }
  __builtin_amdgcn_s_barrier();

#pragma unroll 1
  for (int t=0; t<NT; ++t){
    const int s  = t & 1;
    const int s1 = s ^ 1;
    const char* Ah = (const char*)&smem[s][0][wm][0];
    const char* Bh = (const char*)&smem[s][1][wn>>1][0];
    const int bb = (wn & 1) * 64;

    // P1
#pragma unroll
    for (int mf=0; mf<4; ++mf)
#pragma unroll
      for (int ks=0; ks<2; ++ks){
        const int b = ((mf*16 + l16)*128 + ks*64 + quad*16) ^ sx;
        af[mf][ks] = *reinterpret_cast<const bf16x8*>(Ah + b);
      }
#pragma unroll
    for (int nf=0; nf<2; ++nf)
#pragma unroll
      for (int ks=0; ks<2; ++ks){
        const int b = ((bb + nf*16 + l16)*128 + ks*64 + quad*16) ^ sx;
        bq[nf][ks] = *reinterpret_cast<const bf16x8*>(Bh + b);
      }
    if (t+1 < NT) stage(pA1, t+1, &smem[s1][0][1][0]);
    __builtin_amdgcn_sched_barrier(0);
    __builtin_amdgcn_s_barrier();
    asm volatile("s_waitcnt lgkmcnt(0)" ::: "memory");
    __builtin_amdgcn_sched_barrier(0);
    __builtin_amdgcn_s_setprio(1);
#pragma unroll
    for (int mf=0; mf<4; ++mf)
#pragma unroll
      for (int nf=0; nf<2; ++nf)
#pragma unroll
        for (int ks=0; ks<2; ++ks)
          acc[mf][nf] = __builtin_amdgcn_mfma_f32_16x16x32_bf16(af[mf][ks], bq[nf][ks], acc[mf][nf], 0,0,0);
    __builtin_amdgcn_s_setprio(0);
    __builtin_amdgcn_sched_barrier(0);
    __builtin_amdgcn_s_barrier();

    // P2
#pragma unroll
    for (int nf=0; nf<2; ++nf)
#pragma unroll
      for (int ks=0; ks<2; ++ks){
        const int b = ((bb + (2+nf)*16 + l16)*128 + ks*64 + quad*16) ^ sx;
        bq[2+nf][ks] = *reinterpret_cast<const bf16x8*>(Bh + b);
      }
    if (t+1 < NT) stage(pB0, t+1, &smem[s1][1][0][0]);
    __builtin_amdgcn_sched_barrier(0);
    __builtin_amdgcn_s_barrier();
    asm volatile("s_waitcnt lgkmcnt(0)" ::: "memory");
    __builtin_amdgcn_sched_barrier(0);
    __builtin_amdgcn_s_setprio(1);
#pragma unroll
    for (int mf=0; mf<4; ++mf)
#pragma unroll
      for (int nf=0; nf<2; ++nf)
#pragma unroll
        for (int ks=0; ks<2; ++ks)
          acc[mf][2+nf] = __builtin_amdgcn_mfma_f32_16x16x32_bf16(af[mf][ks], bq[2+nf][ks], acc[mf][2+nf], 0,0,0);
    __builtin_amdgcn_s_setprio(0);
    __builtin_amdgcn_sched_barrier(0);
    __builtin_amdgcn_s_barrier();

    // P3
#pragma unroll
    for (int mf=0; mf<4; ++mf)
#pragma unroll
      for (int ks=0; ks<2; ++ks){
        const int b = ((64 + mf*16 + l16)*128 + ks*64 + quad*16) ^ sx;
        af[mf][ks] = *reinterpret_cast<const bf16x8*>(Ah + b);
      }
    if (t+1 < NT) stage(pB1, t+1, &smem[s1][1][1][0]);
    __builtin_amdgcn_sched_barrier(0);
    __builtin_amdgcn_s_barrier();
    asm volatile("s_waitcnt lgkmcnt(0)" ::: "memory");
    __builtin_amdgcn_sched_barrier(0);
    __builtin_amdgcn_s_setprio(1);
#pragma unroll
    for (int mf=0; mf<4; ++mf)
#pragma unroll
      for (int nf=0; nf<2; ++nf)
#pragma unroll
        for (int ks=0; ks<2; ++ks)
          acc[4+mf][2+nf] = __builtin_amdgcn_mfma_f32_16x16x32_bf16(af[mf][ks], bq[2+nf][ks], acc[4+mf][2+nf], 0,0,0);
    __builtin_amdgcn_s_setprio(0);
    __builtin_amdgcn_sched_barrier(0);
    __builtin_amdgcn_s_barrier();

    // P4
    if (t+2 < NT) stage(pA0, t+2, &smem[s][0][0][0]);
    __builtin_amdgcn_sched_barrier(0);
    __builtin_amdgcn_s_barrier();
    __builtin_amdgcn_s_setprio(1);
#pragma unroll
    for (int mf=0; mf<4; ++mf)
#pragma unroll
      for (int nf=0; nf<2; ++nf)
#pragma unroll
        for (int ks=0; ks<2; ++ks)
          acc[4+mf][nf] = __builtin_amdgcn_mfma_f32_16x16x32_bf16(af[mf][ks], bq[nf][ks], acc[4+mf][nf], 0,0,0);
    __builtin_amdgcn_s_setprio(0);
    __builtin_amdgcn_sched_barrier(0);
    if (t+2 < NT) asm volatile("s_waitcnt vmcnt(2)" ::: "memory");
    else          asm volatile("s_waitcnt vmcnt(0)" ::: "memory");
    __builtin_amdgcn_s_barrier();
  }

#pragma unroll
  for (int i=0;i<8;++i){
    const int row = m0 + wm*128 + (i>>2)*64 + (i&3)*16 + quad*4;
#pragma unroll
    for (int j=0;j<4;++j){
      const int col = n0 + wn*64 + j*16 + l16;
#pragma unroll
      for (int r=0;r<4;++r){
        const float v = acc[i][j][r];
        const size_t idx = (size_t)(row + r)*N + col;
        if (epi==1){ outB[idx] = f2b(v); }
        else {
          const int b = (row + r) >> 11;
          atomicAdd(&dest[idx], gate[b*MODS_STRIDE + col] * v);
        }
      }
    }
  }
}

// -------- batched transpose+convert: dst[c*dstride+doff+r] = f2b(src[r*cols+c])
struct TDesc { const float* src; u16* dst; int rows; int cols; int base; int dstride; int doff; };
struct TPack { TDesc d[16]; };

__global__ __launch_bounds__(256) void transpose_all(TPack p, int nmat)
{
  __shared__ float t[32][33];
  const int bid = blockIdx.x;
  int mi = 0;
#pragma unroll 1
  while (mi+1 < nmat && bid >= p.d[mi+1].base) ++mi;
  const TDesc D = p.d[mi];
  const int tid2   = bid - D.base;
  const int tilesx = D.cols >> 5;
  const int r0 = (tid2 / tilesx) * 32;
  const int c0 = (tid2 % tilesx) * 32;
  const int tx = threadIdx.x & 31, ty = threadIdx.x >> 5;
  for (int i=ty;i<32;i+=8)
    t[i][tx] = D.src[(size_t)(r0+i)*D.cols + c0 + tx];
  __syncthreads();
  for (int i=ty;i<32;i+=8)
    D.dst[(size_t)(c0+i)*D.dstride + D.doff + r0 + tx] = f2b(t[tx][i]);
}

// ---- LoRA fold: WqkvT[n][k] += mag[n>>6] * sum_r la[k][r]*lb[r][n]  (n<1024)
__global__ __launch_bounds__(256) void lora_fold(
    const float* __restrict__ la, const float* __restrict__ lb,
    const float* __restrict__ mag, u16* __restrict__ WqkvT)
{
  const unsigned idx = blockIdx.x*256u + threadIdx.x;   // 1M
  const int k = idx & 1023, n = idx >> 10;
  float s = 0.f;
#pragma unroll
  for (int r=0;r<16;++r)
    s = fmaf(la[k*16+r], lb[r*1024+n], s);
  const float m = mag[n>>6];
  const unsigned o = (unsigned)n*1024u + k;
  WqkvT[o] = f2b(b2f(WqkvT[o]) + m*s);
}

// ---------------- LayerNorm (+ optional modulate, + optional residual copy) ---
__global__ __launch_bounds__(256) void ln_kernel(
    const float* __restrict__ xin,
    const float* __restrict__ w, const float* __restrict__ bias,
    const float* __restrict__ mods, int sh_off, int sc_off,
    u16* __restrict__ out_norm, u16* __restrict__ out_mod,
    float* __restrict__ out_xw)
{
  const int row = blockIdx.x;
  const int b = row >> 11;
  const int t = threadIdx.x;
  float v[4];
#pragma unroll
  for (int e=0;e<4;++e)
    v[e] = xin[(size_t)row*CDIM + t*4+e];
  float s  = v[0]+v[1]+v[2]+v[3];
  float ss = v[0]*v[0]+v[1]*v[1]+v[2]*v[2]+v[3]*v[3];
  s = wredsum(s); ss = wredsum(ss);
  __shared__ float rs[4], rss[4];
  const int wv = t>>6;
  if ((t&63)==0){ rs[wv]=s; rss[wv]=ss; }
  __syncthreads();
  s  = rs[0]+rs[1]+rs[2]+rs[3];
  ss = rss[0]+rss[1]+rss[2]+rss[3];
  const float mean = s * (1.f/1024.f);
  const float var  = ss * (1.f/1024.f) - mean*mean;
  const float rinv = rsqrtf(var + 1e-5f);
#pragma unroll
  for (int e=0;e<4;++e){
    const int c = t*4+e;
    const float nv = (v[e]-mean)*rinv*w[c] + bias[c];
    if (out_norm) out_norm[(size_t)row*CDIM+c] = f2b(nv);
    if (out_mod){
      const float sc = mods[b*MODS_STRIDE + sc_off + c];
      const float sh = mods[b*MODS_STRIDE + sh_off + c];
      out_mod[(size_t)row*CDIM+c] = f2b(nv*(1.f+sc)+sh);
    }
    if (out_xw) out_xw[(size_t)row*CDIM+c] = v[e];
  }
}

// ---------------- adaLN ------------------------------------------------------
__global__ __launch_bounds__(256) void ada_init(
    const float* __restrict__ ab, float* __restrict__ mods)
{
  const int j = blockIdx.x*256 + threadIdx.x;     // < 12288
  const int jj = (j >= MODS_STRIDE) ? j - MODS_STRIDE : j;
  mods[j] = ab[jj];
}

__global__ __launch_bounds__(256) void ada_split(
    const float* __restrict__ cin, const float* __restrict__ aw,
    float* __restrict__ mods)
{
  const int j  = blockIdx.x*256 + threadIdx.x;    // 0..6143
  const int k0 = blockIdx.y*64;
  float s0 = 0.f, s1 = 0.f;
  for (int k=k0; k<k0+64; ++k){
    const float wv = aw[(size_t)k*MODS_STRIDE + j];
    const float c0 = cin[k], c1 = cin[CDIM + k];
    s0 = fmaf(c0*sigm(c0), wv, s0);
    s1 = fmaf(c1*sigm(c1), wv, s1);
  }
  atomicAdd(&mods[j], s0);
  atomicAdd(&mods[MODS_STRIDE + j], s1);
}

// ---------------- MFMA flash attention, 32x32 MFMA + in-register P (T12) -----
// (kept from r11 — inferred ~21 µs/dispatch, down from 86 µs)
__global__ __launch_bounds__(256) void attn_mfma(
    const u16* __restrict__ qkv, u16* __restrict__ AH)
{
  __shared__ u16 Kl[64*64];       // [key][64d] swizzled, 8KB
  __shared__ u16 Vt[64*64];       // [d][64key] swizzled, 8KB
  const int t = threadIdx.x;
  const int w = t>>6, lane = t&63;
  const int l32 = lane & 31, hi = lane >> 5;
  const int qt = blockIdx.x, h = blockIdx.y, b = blockIdx.z;
  const size_t rowbase = (size_t)b*NTOK;

  bf16x8 qf[4];
  {
    const size_t gr = rowbase + qt*128 + w*32 + l32;
    const u16* qp = qkv + gr*3072 + h*64;
#pragma unroll
    for (int ds=0; ds<4; ++ds){
      const u16x8 qa = *reinterpret_cast<const u16x8*>(qp + ds*16 + hi*8);
#pragma unroll
      for (int j=0;j<8;++j)
        qf[ds][j] = (__bf16)(b2f(qa[j]) * 0.125f);
    }
  }

  const u16* ksrc[2]; int kwr[2];
#pragma unroll
  for (int it=0; it<2; ++it){
    const int e = it*256 + t;
    const int key = e>>3, ch = e&7;
    ksrc[it] = qkv + (rowbase + key)*3072 + 1024 + h*64 + ch*8;
    kwr[it]  = key*128 + ((ch ^ (key&7)) << 4);
  }
  const u16* vsrc[2]; int vwr[2][8];
#pragma unroll
  for (int it=0; it<2; ++it){
    const int d0 = (w*2 + it)*8;
    vsrc[it] = qkv + (rowbase + lane)*3072 + 2048 + h*64 + d0;
#pragma unroll
    for (int j=0;j<8;++j){
      const int d = d0 + j;
      vwr[it][j] = d*128 + (((lane>>3) ^ (d&7)) << 4) + (lane&7)*2;
    }
  }
  int kra[2][4];
#pragma unroll
  for (int st=0; st<2; ++st)
#pragma unroll
    for (int ds=0; ds<4; ++ds){
      const int key = st*32 + l32;
      kra[st][ds] = key*128 + (((ds*2 + hi) ^ (key&7)) << 4);
    }
  int vra[2][2][2];
#pragma unroll
  for (int st=0; st<2; ++st)
#pragma unroll
    for (int ks=0; ks<2; ++ks)
#pragma unroll
      for (int dt=0; dt<2; ++dt){
        const int d = dt*32 + l32;
        vra[st][ks][dt] = d*128 + (((st*4 + ks*2 + hi) ^ (d&7)) << 4);
      }

  const size_t KSTRIDE = (size_t)64*3072;

  u16x8 kA[2], vA[2], kB[2], vB[2];
#pragma unroll
  for (int it=0; it<2; ++it){
    kA[it] = *reinterpret_cast<const u16x8*>(ksrc[it]);
    vA[it] = *reinterpret_cast<const u16x8*>(vsrc[it]);
  }

  float l_part = 0.f;
  f32x16 oacc[2] = {};

  auto step = [&](u16x8 (&kk)[2], u16x8 (&vv)[2], int kbn,
                  u16x8 (&kn)[2], u16x8 (&vn)[2]){
#pragma unroll
    for (int it=0; it<2; ++it){
      *reinterpret_cast<u16x8*>((char*)Kl + kwr[it]) = kk[it];
#pragma unroll
      for (int j=0;j<8;++j)
        *reinterpret_cast<u16*>((char*)Vt + vwr[it][j]) = vv[it][j];
    }
    __syncthreads();
    {
      const size_t off = (size_t)kbn * KSTRIDE;
#pragma unroll
      for (int it=0; it<2; ++it){
        kn[it] = *reinterpret_cast<const u16x8*>(ksrc[it] + off);
        vn[it] = *reinterpret_cast<const u16x8*>(vsrc[it] + off);
      }
    }
    f32x16 sacc[2] = {};
#pragma unroll
    for (int st=0; st<2; ++st)
#pragma unroll
      for (int ds=0; ds<4; ++ds){
        const bf16x8 af = *reinterpret_cast<const bf16x8*>((char*)Kl + kra[st][ds]);
        sacc[st] = __builtin_amdgcn_mfma_f32_32x32x16_bf16(af, qf[ds], sacc[st], 0,0,0);
      }
#pragma unroll
    for (int st=0; st<2; ++st)
#pragma unroll
      for (int r=0;r<16;++r){
        const float pv = __expf(sacc[st][r]);
        sacc[st][r] = pv;
        l_part += pv;
      }
#pragma unroll
    for (int st=0; st<2; ++st){
      unsigned wd[8];
#pragma unroll
      for (int m=0;m<8;++m)
        wd[m] = cvt_pk_bf16(sacc[st][2*m], sacc[st][2*m+1]);
      permlane32_swap(wd[0], wd[2]);
      permlane32_swap(wd[1], wd[3]);
      permlane32_swap(wd[4], wd[6]);
      permlane32_swap(wd[5], wd[7]);
      u32x4 paw[2];
      paw[0] = u32x4{wd[0], wd[1], wd[2], wd[3]};
      paw[1] = u32x4{wd[4], wd[5], wd[6], wd[7]};
#pragma unroll
      for (int ks=0; ks<2; ++ks){
        const bf16x8 pa = *reinterpret_cast<const bf16x8*>(&paw[ks]);
#pragma unroll
        for (int dt=0; dt<2; ++dt){
          const bf16x8 vb = *reinterpret_cast<const bf16x8*>((char*)Vt + vra[st][ks][dt]);
          oacc[dt] = __builtin_amdgcn_mfma_f32_32x32x16_bf16(pa, vb, oacc[dt], 0,0,0);
        }
      }
    }
    __syncthreads();
  };

#pragma unroll 1
  for (int kb=0; kb<32; kb+=2){
    step(kA, vA, (kb+1 < 32 ? kb+1 : 31), kB, vB);
    step(kB, vB, (kb+2 < 32 ? kb+2 : 31), kA, vA);
  }

  const float l_run = l_part + __shfl_xor(l_part, 32);

#pragma unroll
  for (int r=0;r<16;++r){
    const int crow = (r&3) + 8*(r>>2) + 4*hi;
    const float li = __shfl(l_run, crow);
    const size_t grow = rowbase + qt*128 + w*32 + crow;
#pragma unroll
    for (int dt=0; dt<2; ++dt)
      AH[grow*2048 + h*64 + dt*32 + l32] = f2b(oacc[dt][r] / li);
  }
}

// ---------------- HGRN chunked scan (32 chunks of 64) --------------------------
__global__ __launch_bounds__(256) void scan_p1(
    const u16* __restrict__ FIG, float* __restrict__ cA, float* __restrict__ cH)
{
  const unsigned int idx = blockIdx.x*256u + threadIdx.x;
  const unsigned int c = idx & 1023u, chunk = (idx>>10)&(NCHUNK-1), b = idx>>15;
  float A = 1.f, h = 0.f;
  const size_t base = ((size_t)b*NTOK + chunk*CHLEN) * 3072;
  for (int t=0;t<CHLEN;++t){
    const float F = b2f(FIG[base + (size_t)t*3072 + c]);
    const float I = b2f(FIG[base + (size_t)t*3072 + 1024 + c]);
    const float f = sigm(F);
    const float il = I*sigm(I) * (1.f - f);
    A *= f;
    h = fmaf(f, h, il);
  }
  cA[idx] = A; cH[idx] = h;
}

__global__ __launch_bounds__(256) void scan_p2(
    const float* __restrict__ cA, const float* __restrict__ cH, float* __restrict__ Hinit)
{
  const unsigned int idx = blockIdx.x*256u + threadIdx.x;  // [0,2048)
  const unsigned int b = idx>>10, c = idx&1023u;
  float h = 0.f;
#pragma unroll
  for (int ch=0;ch<NCHUNK;++ch){
    const unsigned int q = (b*NCHUNK + ch)*1024 + c;
    Hinit[q] = h;
    h = fmaf(cA[q], h, cH[q]);
  }
}

__global__ __launch_bounds__(256) void scan_p3(
    const u16* __restrict__ FIG, const float* __restrict__ Hinit, u16* __restrict__ Hb)
{
  const unsigned int idx = blockIdx.x*256u + threadIdx.x;
  const unsigned int c = idx & 1023u, chunk = (idx>>10)&(NCHUNK-1), b = idx>>15;
  float h = Hinit[idx];
  const size_t base = ((size_t)b*NTOK + chunk*CHLEN) * 3072;
  const size_t obase = ((size_t)b*NTOK + chunk*CHLEN) * CDIM;
  for (int t=0;t<CHLEN;++t){
    const float F = b2f(FIG[base + (size_t)t*3072 + c]);
    const float I = b2f(FIG[base + (size_t)t*3072 + 1024 + c]);
    const float f = sigm(F);
    const float il = I*sigm(I) * (1.f - f);
    h = fmaf(f, h, il);
    Hb[obase + (size_t)t*CDIM + c] = f2b(h);
  }
}

// ---------------- HGRN post: per-head RMSNorm * gn * silu(G) -------------------
__global__ __launch_bounds__(256) void hgrn_post(
    const u16* __restrict__ Hb, const u16* __restrict__ FIG,
    const float* __restrict__ gn, u16* __restrict__ AH)
{
  const int row = blockIdx.x;
  const int t = threadIdx.x;
  float hv[4]; float ss = 0.f;
#pragma unroll
  for (int e=0;e<4;++e){
    hv[e] = b2f(Hb[(size_t)row*CDIM + t*4 + e]);
    ss = fmaf(hv[e], hv[e], ss);
  }
#pragma unroll
  for (int o=1;o<16;o<<=1) ss += __shfl_xor(ss, o);
  const float rinv = rsqrtf(ss*(1.f/64.f) + 1e-5f);
#pragma unroll
  for (int e=0;e<4;++e){
    const int c = t*4+e;
    const float g = b2f(FIG[(size_t)row*3072 + 2048 + c]);
    AH[(size_t)row*2048 + 1024 + c] = f2b(hv[e]*rinv*gn[c] * g*sigm(g));
  }
}

// ---------------- MLP activation: silu(gate)*val -------------------------------
__global__ __launch_bounds__(256) void act_kernel(
    const u16* __restrict__ U, u16* __restrict__ A)
{
  const unsigned int i = blockIdx.x*256u + threadIdx.x;
  const unsigned int r = i / INTERDIM, j = i % INTERDIM;
  const float g = b2f(U[(size_t)r*(2*INTERDIM) + j]);
  const float v = b2f(U[(size_t)r*(2*INTERDIM) + INTERDIM + j]);
  A[i] = f2b(g*sigm(g)*v);
}

__global__ __launch_bounds__(256) void store_out(
    const float* __restrict__ xw, float* __restrict__ out)
{
  const unsigned int i = blockIdx.x*256u + threadIdx.x;
  out[i] = xw[i];
}

__global__ __launch_bounds__(256) void fill_fail(float* __restrict__ out)
{
  const unsigned int i = blockIdx.x*256u + threadIdx.x;
  out[i] = 1234.5f;
}

// ---------------- host orchestration ------------------------------------------
static void run_stream(hipStream_t stream,
    const float* Xin, const float* LNW, const float* LNB,
    const float* MAG, const float* LA, const float* LBw, const float* GN,
    float* mods, float* xw, float* outp,
    u16* WqkvT, const u16* WpwT, const u16* WhgrnT,
    const u16* WgateT, const u16* WdownT,
    u16* x_norm, u16* v_h, u16* qkvb, u16* delta, u16* AH,
    float* cA, float* cH, float* Hinit, u16* U, u16* actb)
{
  u16* FIG    = qkvb;
  u16* Hb     = delta;
  u16* mlp_in = x_norm;

  lora_fold<<<4096,256,0,stream>>>(LA, LBw, MAG, WqkvT);

  ln_kernel<<<ROWS,256,0,stream>>>(Xin, LNW, LNB, mods, 0, 1024, x_norm, v_h, xw);

  // attention branch -> AH[:,0:1024]
  gemm_bt<<<dim3(12,16),512,0,stream>>>(x_norm, WqkvT, ROWS,3072,1024, 1, qkvb, nullptr, nullptr);
  attn_mfma<<<dim3(16,16,2),256,0,stream>>>(qkvb, AH);

  // HGRN branch -> AH[:,1024:2048]
  gemm_bt<<<dim3(12,16),512,0,stream>>>(v_h, WhgrnT, ROWS,3072,1024, 1, FIG, nullptr, nullptr);
  scan_p1<<<2*NCHUNK*1024/256,256,0,stream>>>(FIG, cA, cH);
  scan_p2<<<8,256,0,stream>>>(cA, cH, Hinit);
  scan_p3<<<2*NCHUNK*1024/256,256,0,stream>>>(FIG, Hinit, Hb);
  hgrn_post<<<ROWS,256,0,stream>>>(Hb, FIG, GN, AH);

  // fused proj+wo: xw += g_msa * (AH @ [Wproj;Wwo]^T), split-K=4
  gemm_bt<<<dim3(4,16,4),512,0,stream>>>(AH, WpwT, ROWS,1024,2048, 2, nullptr, xw, mods+2048);

  // MLP (r4 form: gate GEMM -> U, separate activation kernel)
  ln_kernel<<<ROWS,256,0,stream>>>(xw, LNW, LNB, mods, 3072, 4096, nullptr, mlp_in, nullptr);
  gemm_bt<<<dim3(22,16),512,0,stream>>>(mlp_in, WgateT, ROWS,5632,1024, 1, U, nullptr, nullptr);
  act_kernel<<<ROWS*INTERDIM/256,256,0,stream>>>(U, actb);
  // down-proj split-K=4: xw += g_mlp * (act @ Wdown^T)
  gemm_bt<<<dim3(4,16,4),512,0,stream>>>(actb, WdownT, ROWS,1024,2816, 2, nullptr, xw, mods+5120);

  store_out<<<ROWS*CDIM/256,256,0,stream>>>(xw, outp);
}

extern "C" void kernel_launch(void* const* d_in, const int* in_sizes, int n_in,
                              void* d_out, int out_size, void* d_ws, size_t ws_size,
                              hipStream_t stream)
{
  const float* X    = (const float*)d_in[0];
  const float* Y    = (const float*)d_in[1];
  const float* Cc   = (const float*)d_in[2];
  const float* GXW  = (const float*)d_in[3];
  const float* GXB  = (const float*)d_in[4];
  const float* GYW  = (const float*)d_in[5];
  const float* GYB  = (const float*)d_in[6];
  const float* ADAW = (const float*)d_in[7];
  const float* ADAB = (const float*)d_in[8];
  const float* XY_QKV = (const float*)d_in[9];
  const float* XY_MAG = (const float*)d_in[10];
  const float* XY_LA  = (const float*)d_in[11];
  const float* XY_LB  = (const float*)d_in[12];
  const float* XY_PROJ= (const float*)d_in[13];
  const float* YX_QKV = (const float*)d_in[14];
  const float* YX_MAG = (const float*)d_in[15];
  const float* YX_LA  = (const float*)d_in[16];
  const float* YX_LB  = (const float*)d_in[17];
  const float* YX_PROJ= (const float*)d_in[18];
  const float* AX_WI = (const float*)d_in[19];
  const float* AX_WF = (const float*)d_in[20];
  const float* AX_WG = (const float*)d_in[21];
  const float* AX_WO = (const float*)d_in[22];
  const float* AX_GN = (const float*)d_in[23];
  const float* AY_WI = (const float*)d_in[24];
  const float* AY_WF = (const float*)d_in[25];
  const float* AY_WG = (const float*)d_in[26];
  const float* AY_WO = (const float*)d_in[27];
  const float* AY_GN = (const float*)d_in[28];
  const float* MX_GATE = (const float*)d_in[29];
  const float* MX_DOWN = (const float*)d_in[30];
  const float* MY_GATE = (const float*)d_in[31];
  const float* MY_DOWN = (const float*)d_in[32];
  float* OUT = (float*)d_out;

  char* p = (char*)d_ws;
  size_t off = 0;
  auto alloc = [&](size_t bytes)->char*{
    char* r = p + off;
    off = (off + bytes + 255) & ~(size_t)255;
    return r;
  };
  float* mods  = (float*)alloc(2*MODS_STRIDE*sizeof(float));
  float* xw_x  = (float*)alloc((size_t)ROWS*CDIM*sizeof(float));
  float* xw_y  = (float*)alloc((size_t)ROWS*CDIM*sizeof(float));
  u16* WqkvT0  = (u16*)alloc((size_t)3072*1024*2);
  u16* WqkvT1  = (u16*)alloc((size_t)3072*1024*2);
  u16* WpwT0   = (u16*)alloc((size_t)1024*2048*2);
  u16* WpwT1   = (u16*)alloc((size_t)1024*2048*2);
  u16* WhgrnT0 = (u16*)alloc((size_t)3072*1024*2);
  u16* WhgrnT1 = (u16*)alloc((size_t)3072*1024*2);
  u16* WgateT0 = (u16*)alloc((size_t)5632*1024*2);
  u16* WgateT1 = (u16*)alloc((size_t)5632*1024*2);
  u16* WdownT0 = (u16*)alloc((size_t)1024*2816*2);
  u16* WdownT1 = (u16*)alloc((size_t)1024*2816*2);
  u16* x_norm  = (u16*)alloc((size_t)ROWS*CDIM*2);
  u16* v_h     = (u16*)alloc((size_t)ROWS*CDIM*2);
  u16* qkvb    = (u16*)alloc((size_t)ROWS*3072*2);
  u16* delta   = (u16*)alloc((size_t)ROWS*CDIM*2);
  u16* AH      = (u16*)alloc((size_t)ROWS*2048*2);
  float* cA    = (float*)alloc((size_t)2*NCHUNK*1024*sizeof(float));
  float* cH    = (float*)alloc((size_t)2*NCHUNK*1024*sizeof(float));
  float* Hinit = (float*)alloc((size_t)2*NCHUNK*1024*sizeof(float));
  u16* U       = (u16*)alloc((size_t)ROWS*5632*2);
  u16* actb    = (u16*)alloc((size_t)ROWS*INTERDIM*2);

  if (off > ws_size){
    fill_fail<<<(2*ROWS*CDIM)/256,256,0,stream>>>(OUT);
    return;
  }

  ada_init<<<2*MODS_STRIDE/256,256,0,stream>>>(ADAB, mods);
  ada_split<<<dim3(MODS_STRIDE/256,16),256,0,stream>>>(Cc, ADAW, mods);

  TPack tp; int base = 0; int ndesc = 0;
  auto add = [&](const float* s, u16* d2, int rows, int cols, int dstride, int doff){
    tp.d[ndesc].src = s; tp.d[ndesc].dst = d2;
    tp.d[ndesc].rows = rows; tp.d[ndesc].cols = cols; tp.d[ndesc].base = base;
    tp.d[ndesc].dstride = dstride; tp.d[ndesc].doff = doff;
    base += (rows>>5)*(cols>>5); ++ndesc;
  };
  add(XY_QKV,  WqkvT0, 1024, 3072, 1024, 0);
  add(XY_PROJ, WpwT0,  1024, 1024, 2048, 0);
  add(AX_WO,   WpwT0,  1024, 1024, 2048, 1024);
  add(AX_WF, WhgrnT0,               1024, 1024, 1024, 0);
  add(AX_WI, WhgrnT0 + 1024*1024,   1024, 1024, 1024, 0);
  add(AX_WG, WhgrnT0 + 2*1024*1024, 1024, 1024, 1024, 0);
  add(MX_GATE, WgateT0, 1024, 5632, 1024, 0);
  add(MX_DOWN, WdownT0, 2816, 1024, 2816, 0);
  add(YX_QKV,  WqkvT1, 1024, 3072, 1024, 0);
  add(YX_PROJ, WpwT1,  1024, 1024, 2048, 0);
  add(AY_WO,   WpwT1,  1024, 1024, 2048, 1024);
  add(AY_WF, WhgrnT1,               1024, 1024, 1024, 0);
  add(AY_WI, WhgrnT1 + 1024*1024,   1024, 1024, 1024, 0);
  add(AY_WG, WhgrnT1 + 2*1024*1024, 1024, 1024, 1024, 0);
  add(MY_GATE, WgateT1, 1024, 5632, 1024, 0);
  add(MY_DOWN, WdownT1, 2816, 1024, 2816, 0);
  transpose_all<<<base,256,0,stream>>>(tp, ndesc);

  run_stream(stream, X, GXW, GXB, XY_MAG, XY_LA, XY_LB, AX_GN,
             mods, xw_x, OUT,
             WqkvT0, WpwT0, WhgrnT0, WgateT0, WdownT0,
             x_norm, v_h, qkvb, delta, AH,
             cA, cH, Hinit, U, actb);

  run_stream(stream, Y, GYW, GYB, YX_MAG, YX_LA, YX_LB, AY_GN,
             mods, xw_y, OUT + (size_t)ROWS*CDIM,
             WqkvT1, WpwT1, WhgrnT1, WgateT1, WdownT1,
             x_norm, v_h, qkvb, delta, AH,
             cA, cH, Hinit, U, actb);
}

// Round 15
// 1175.046 us; speedup vs baseline: 1.0868x; 1.0357x over previous
//
#include <hip/hip_runtime.h>
#include <stdint.h>

#define NTOK 2048
#define CDIM 1024
#define ROWS 4096          // B*N
#define MODS_STRIDE 6144
#define INTERDIM 2816
#define NCHUNK 32
#define CHLEN (NTOK/NCHUNK)   // 64

typedef unsigned short u16;
typedef __bf16 bf16x8 __attribute__((ext_vector_type(8)));
typedef float f32x4 __attribute__((ext_vector_type(4)));
typedef float f32x16 __attribute__((ext_vector_type(16)));
typedef u16 u16x8 __attribute__((ext_vector_type(8)));
typedef unsigned int u32x4 __attribute__((ext_vector_type(4)));

__device__ __forceinline__ float b2f(u16 u){
  union { unsigned int i; float f; } v; v.i = ((unsigned int)u) << 16; return v.f;
}
__device__ __forceinline__ u16 f2b(float f){
  union { float f; unsigned int i; } v; v.f = f;
  unsigned int i = v.i;
  unsigned int r = i + 0x7FFFu + ((i >> 16) & 1u);
  return (u16)(r >> 16);
}
__device__ __forceinline__ float sigm(float x){ return 1.f/(1.f+__expf(-x)); }
__device__ __forceinline__ float wredsum(float v){
#pragma unroll
  for (int o=32;o>0;o>>=1) v += __shfl_xor(v,o);
  return v;
}
__device__ __forceinline__ void async16(const void* g, void* l){
  __builtin_amdgcn_global_load_lds(
      (const __attribute__((address_space(1))) unsigned int*)g,
      (__attribute__((address_space(3))) unsigned int*)l, 16, 0, 0);
}
__device__ __forceinline__ unsigned cvt_pk_bf16(float lo, float hi){
  unsigned r;
  asm("v_cvt_pk_bf16_f32 %0, %1, %2" : "=v"(r) : "v"(lo), "v"(hi));
  return r;
}
__device__ __forceinline__ void permlane32_swap(unsigned &a, unsigned &b){
  // after: a = {A[0:31], B[0:31]}, b = {A[32:63], B[32:63]}
  asm volatile("v_permlane32_swap_b32 %0, %1" : "+v"(a), "+v"(b));
}

// ---------------- 256x256 8-wave MFMA GEMM: C[M,N] = A[M,K] @ Bt[N,K]^T -----
// 8-phase schedule (verified r13). epi==1: bf16 store. epi==2: gated atomicAdd.
__global__ __launch_bounds__(512) void gemm_bt(
    const u16* __restrict__ Ain, const u16* __restrict__ Bt,
    int M, int N, int K, int epi,
    u16* __restrict__ outB,
    float* __restrict__ dest, const float* __restrict__ gate)
{
  __shared__ u16 smem[2][2][2][8192];   // [slot][A=0/B=1][half][128x64], 128 KiB

  const int nwg  = gridDim.x * gridDim.y;
  const int orig = blockIdx.y * gridDim.x + blockIdx.x;
  const int qch  = nwg >> 3, rch = nwg & 7;
  const int xcd  = orig & 7, loc = orig >> 3;
  const int swzb = (xcd < rch ? xcd*(qch+1) : rch*(qch+1) + (xcd-rch)*qch) + loc;
  const int m0 = (swzb / gridDim.x) * 256;
  const int n0 = (swzb % gridDim.x) * 256;

  const int kchunk = K / gridDim.z;
  const int kbase  = blockIdx.z * kchunk;
  const int NT = kchunk >> 6;

  const int tid = threadIdx.x;
  const int w = tid >> 6, lane = tid & 63;
  const int quad = lane >> 4, l16 = lane & 15;
  const int wm = w >> 2, wn = w & 3;
  const int sx = (l16 & 7) << 4;

  int soff[2];
#pragma unroll
  for (int j=0;j<2;++j){
    const int row = (w*2 + j)*8 + (lane >> 3);
    soff[j] = row*(K*2) + (((lane & 7) ^ (row & 7)) << 4);
  }

  const char* pA0 = (const char*)(Ain + (size_t)m0*K       + kbase);
  const char* pA1 = (const char*)(Ain + (size_t)(m0+128)*K + kbase);
  const char* pB0 = (const char*)(Bt  + (size_t)n0*K       + kbase);
  const char* pB1 = (const char*)(Bt  + (size_t)(n0+128)*K + kbase);

  auto stage = [&](const char* base, int t, u16* region){
#pragma unroll
    for (int j=0;j<2;++j)
      async16(base + (size_t)t*128 + soff[j], (char*)region + (w*2+j)*1024);
  };

  f32x4 acc[8][4] = {};
  bf16x8 af[4][2];
  bf16x8 bq[4][2];

  stage(pA0, 0, &smem[0][0][0][0]);
  stage(pA1, 0, &smem[0][0][1][0]);
  stage(pB0, 0, &smem[0][1][0][0]);
  stage(pB1, 0, &smem[0][1][1][0]);
  if (NT > 1){
    stage(pA0, 1, &smem[1][0][0][0]);
    asm volatile("s_waitcnt vmcnt(2)" ::: "memory");
  } else {
    asm volatile("s_waitcnt vmcnt(0)" ::: "memory");
  }
  __builtin_amdgcn_s_barrier();

#pragma unroll 1
  for (int t=0; t<NT; ++t){
    const int s  = t & 1;
    const int s1 = s ^ 1;
    const char* Ah = (const char*)&smem[s][0][wm][0];
    const char* Bh = (const char*)&smem[s][1][wn>>1][0];
    const int bb = (wn & 1) * 64;

    // P1
#pragma unroll
    for (int mf=0; mf<4; ++mf)
#pragma unroll
      for (int ks=0; ks<2; ++ks){
        const int b = ((mf*16 + l16)*128 + ks*64 + quad*16) ^ sx;
        af[mf][ks] = *reinterpret_cast<const bf16x8*>(Ah + b);
      }
#pragma unroll
    for (int nf=0; nf<2; ++nf)
#pragma unroll
      for (int ks=0; ks<2; ++ks){
        const int b = ((bb + nf*16 + l16)*128 + ks*64 + quad*16) ^ sx;
        bq[nf][ks] = *reinterpret_cast<const bf16x8*>(Bh + b);
      }
    if (t+1 < NT) stage(pA1, t+1, &smem[s1][0][1][0]);
    __builtin_amdgcn_sched_barrier(0);
    __builtin_amdgcn_s_barrier();
    asm volatile("s_waitcnt lgkmcnt(0)" ::: "memory");
    __builtin_amdgcn_sched_barrier(0);
    __builtin_amdgcn_s_setprio(1);
#pragma unroll
    for (int mf=0; mf<4; ++mf)
#pragma unroll
      for (int nf=0; nf<2; ++nf)
#pragma unroll
        for (int ks=0; ks<2; ++ks)
          acc[mf][nf] = __builtin_amdgcn_mfma_f32_16x16x32_bf16(af[mf][ks], bq[nf][ks], acc[mf][nf], 0,0,0);
    __builtin_amdgcn_s_setprio(0);
    __builtin_amdgcn_sched_barrier(0);
    __builtin_amdgcn_s_barrier();

    // P2
#pragma unroll
    for (int nf=0; nf<2; ++nf)
#pragma unroll
      for (int ks=0; ks<2; ++ks){
        const int b = ((bb + (2+nf)*16 + l16)*128 + ks*64 + quad*16) ^ sx;
        bq[2+nf][ks] = *reinterpret_cast<const bf16x8*>(Bh + b);
      }
    if (t+1 < NT) stage(pB0, t+1, &smem[s1][1][0][0]);
    __builtin_amdgcn_sched_barrier(0);
    __builtin_amdgcn_s_barrier();
    asm volatile("s_waitcnt lgkmcnt(0)" ::: "memory");
    __builtin_amdgcn_sched_barrier(0);
    __builtin_amdgcn_s_setprio(1);
#pragma unroll
    for (int mf=0; mf<4; ++mf)
#pragma unroll
      for (int nf=0; nf<2; ++nf)
#pragma unroll
        for (int ks=0; ks<2; ++ks)
          acc[mf][2+nf] = __builtin_amdgcn_mfma_f32_16x16x32_bf16(af[mf][ks], bq[2+nf][ks], acc[mf][2+nf], 0,0,0);
    __builtin_amdgcn_s_setprio(0);
    __builtin_amdgcn_sched_barrier(0);
    __builtin_amdgcn_s_barrier();

    // P3
#pragma unroll
    for (int mf=0; mf<4; ++mf)
#pragma unroll
      for (int ks=0; ks<2; ++ks){
        const int b = ((64 + mf*16 + l16)*128 + ks*64 + quad*16) ^ sx;
        af[mf][ks] = *reinterpret_cast<const bf16x8*>(Ah + b);
      }
    if (t+1 < NT) stage(pB1, t+1, &smem[s1][1][1][0]);
    __builtin_amdgcn_sched_barrier(0);
    __builtin_amdgcn_s_barrier();
    asm volatile("s_waitcnt lgkmcnt(0)" ::: "memory");
    __builtin_amdgcn_sched_barrier(0);
    __builtin_amdgcn_s_setprio(1);
#pragma unroll
    for (int mf=0; mf<4; ++mf)
#pragma unroll
      for (int nf=0; nf<2; ++nf)
#pragma unroll
        for (int ks=0; ks<2; ++ks)
          acc[4+mf][2+nf] = __builtin_amdgcn_mfma_f32_16x16x32_bf16(af[mf][ks], bq[2+nf][ks], acc[4+mf][2+nf], 0,0,0);
    __builtin_amdgcn_s_setprio(0);
    __builtin_amdgcn_sched_barrier(0);
    __builtin_amdgcn_s_barrier();

    // P4
    if (t+2 < NT) stage(pA0, t+2, &smem[s][0][0][0]);
    __builtin_amdgcn_sched_barrier(0);
    __builtin_amdgcn_s_barrier();
    __builtin_amdgcn_s_setprio(1);
#pragma unroll
    for (int mf=0; mf<4; ++mf)
#pragma unroll
      for (int nf=0; nf<2; ++nf)
#pragma unroll
        for (int ks=0; ks<2; ++ks)
          acc[4+mf][nf] = __builtin_amdgcn_mfma_f32_16x16x32_bf16(af[mf][ks], bq[nf][ks], acc[4+mf][nf], 0,0,0);
    __builtin_amdgcn_s_setprio(0);
    __builtin_amdgcn_sched_barrier(0);
    if (t+2 < NT) asm volatile("s_waitcnt vmcnt(2)" ::: "memory");
    else          asm volatile("s_waitcnt vmcnt(0)" ::: "memory");
    __builtin_amdgcn_s_barrier();
  }

#pragma unroll
  for (int i=0;i<8;++i){
    const int row = m0 + wm*128 + (i>>2)*64 + (i&3)*16 + quad*4;
#pragma unroll
    for (int j=0;j<4;++j){
      const int col = n0 + wn*64 + j*16 + l16;
#pragma unroll
      for (int r=0;r<4;++r){
        const float v = acc[i][j][r];
        const size_t idx = (size_t)(row + r)*N + col;
        if (epi==1){ outB[idx] = f2b(v); }
        else {
          const int b = (row + r) >> 11;
          atomicAdd(&dest[idx], gate[b*MODS_STRIDE + col] * v);
        }
      }
    }
  }
}

// -------- batched transpose+convert, 64x64 tiles, fully-coalesced both sides --
// dst[c*dstride+doff+r] = f2b(src[r*cols+c]); writes packed u32 (2x bf16).
struct TDesc { const float* src; u16* dst; int rows; int cols; int base; int dstride; int doff; };
struct TPack { TDesc d[16]; };

__global__ __launch_bounds__(256) void transpose_all(TPack p, int nmat)
{
  __shared__ float t[64][65];
  const int bid = blockIdx.x;
  int mi = 0;
#pragma unroll 1
  while (mi+1 < nmat && bid >= p.d[mi+1].base) ++mi;
  const TDesc D = p.d[mi];
  const int tid2   = bid - D.base;
  const int tilesx = D.cols >> 6;
  const int r0 = (tid2 / tilesx) * 64;
  const int c0 = (tid2 % tilesx) * 64;
  const int tx = threadIdx.x & 63, ty = threadIdx.x >> 6;     // 64 x 4 read
  for (int i=ty;i<64;i+=4)
    t[i][tx] = D.src[(size_t)(r0+i)*D.cols + c0 + tx];
  __syncthreads();
  const int wx = threadIdx.x & 31, wy = threadIdx.x >> 5;     // 32 x 8 write
  for (int c=wy;c<64;c+=8){
    const unsigned lo = f2b(t[2*wx  ][c]);
    const unsigned hi = f2b(t[2*wx+1][c]);
    *reinterpret_cast<unsigned*>(&D.dst[(size_t)(c0+c)*D.dstride + D.doff + r0 + 2*wx]) = lo | (hi<<16);
  }
}

// ---- LoRA fold: WqkvT[n][k] += mag[n>>6] * sum_r la[k][r]*lb[r][n]  (n<1024)
__global__ __launch_bounds__(256) void lora_fold(
    const float* __restrict__ la, const float* __restrict__ lb,
    const float* __restrict__ mag, u16* __restrict__ WqkvT)
{
  const unsigned idx = blockIdx.x*256u + threadIdx.x;   // 1M
  const int k = idx & 1023, n = idx >> 10;
  float s = 0.f;
#pragma unroll
  for (int r=0;r<16;++r)
    s = fmaf(la[k*16+r], lb[r*1024+n], s);
  const float m = mag[n>>6];
  const unsigned o = (unsigned)n*1024u + k;
  WqkvT[o] = f2b(b2f(WqkvT[o]) + m*s);
}

// ---------------- LayerNorm (+ optional modulate, + optional residual copy) ---
__global__ __launch_bounds__(256) void ln_kernel(
    const float* __restrict__ xin,
    const float* __restrict__ w, const float* __restrict__ bias,
    const float* __restrict__ mods, int sh_off, int sc_off,
    u16* __restrict__ out_norm, u16* __restrict__ out_mod,
    float* __restrict__ out_xw)
{
  const int row = blockIdx.x;
  const int b = row >> 11;
  const int t = threadIdx.x;
  float v[4];
#pragma unroll
  for (int e=0;e<4;++e)
    v[e] = xin[(size_t)row*CDIM + t*4+e];
  float s  = v[0]+v[1]+v[2]+v[3];
  float ss = v[0]*v[0]+v[1]*v[1]+v[2]*v[2]+v[3]*v[3];
  s = wredsum(s); ss = wredsum(ss);
  __shared__ float rs[4], rss[4];
  const int wv = t>>6;
  if ((t&63)==0){ rs[wv]=s; rss[wv]=ss; }
  __syncthreads();
  s  = rs[0]+rs[1]+rs[2]+rs[3];
  ss = rss[0]+rss[1]+rss[2]+rss[3];
  const float mean = s * (1.f/1024.f);
  const float var  = ss * (1.f/1024.f) - mean*mean;
  const float rinv = rsqrtf(var + 1e-5f);
#pragma unroll
  for (int e=0;e<4;++e){
    const int c = t*4+e;
    const float nv = (v[e]-mean)*rinv*w[c] + bias[c];
    if (out_norm) out_norm[(size_t)row*CDIM+c] = f2b(nv);
    if (out_mod){
      const float sc = mods[b*MODS_STRIDE + sc_off + c];
      const float sh = mods[b*MODS_STRIDE + sh_off + c];
      out_mod[(size_t)row*CDIM+c] = f2b(nv*(1.f+sc)+sh);
    }
    if (out_xw) out_xw[(size_t)row*CDIM+c] = v[e];
  }
}

// ---------------- adaLN ------------------------------------------------------
__global__ __launch_bounds__(256) void ada_init(
    const float* __restrict__ ab, float* __restrict__ mods)
{
  const int j = blockIdx.x*256 + threadIdx.x;     // < 12288
  const int jj = (j >= MODS_STRIDE) ? j - MODS_STRIDE : j;
  mods[j] = ab[jj];
}

__global__ __launch_bounds__(256) void ada_split(
    const float* __restrict__ cin, const float* __restrict__ aw,
    float* __restrict__ mods)
{
  const int j  = blockIdx.x*256 + threadIdx.x;    // 0..6143
  const int k0 = blockIdx.y*64;
  float s0 = 0.f, s1 = 0.f;
  for (int k=k0; k<k0+64; ++k){
    const float wv = aw[(size_t)k*MODS_STRIDE + j];
    const float c0 = cin[k], c1 = cin[CDIM + k];
    s0 = fmaf(c0*sigm(c0), wv, s0);
    s1 = fmaf(c1*sigm(c1), wv, s1);
  }
  atomicAdd(&mods[j], s0);
  atomicAdd(&mods[MODS_STRIDE + j], s1);
}

// ---------------- MFMA flash attention, 32x32 MFMA + in-register P (T12) -----
// (verified r13 — out of top-5, ~21 µs/dispatch)
__global__ __launch_bounds__(256) void attn_mfma(
    const u16* __restrict__ qkv, u16* __restrict__ AH)
{
  __shared__ u16 Kl[64*64];       // [key][64d] swizzled, 8KB
  __shared__ u16 Vt[64*64];       // [d][64key] swizzled, 8KB
  const int t = threadIdx.x;
  const int w = t>>6, lane = t&63;
  const int l32 = lane & 31, hi = lane >> 5;
  const int qt = blockIdx.x, h = blockIdx.y, b = blockIdx.z;
  const size_t rowbase = (size_t)b*NTOK;

  bf16x8 qf[4];
  {
    const size_t gr = rowbase + qt*128 + w*32 + l32;
    const u16* qp = qkv + gr*3072 + h*64;
#pragma unroll
    for (int ds=0; ds<4; ++ds){
      const u16x8 qa = *reinterpret_cast<const u16x8*>(qp + ds*16 + hi*8);
#pragma unroll
      for (int j=0;j<8;++j)
        qf[ds][j] = (__bf16)(b2f(qa[j]) * 0.125f);
    }
  }

  const u16* ksrc[2]; int kwr[2];
#pragma unroll
  for (int it=0; it<2; ++it){
    const int e = it*256 + t;
    const int key = e>>3, ch = e&7;
    ksrc[it] = qkv + (rowbase + key)*3072 + 1024 + h*64 + ch*8;
    kwr[it]  = key*128 + ((ch ^ (key&7)) << 4);
  }
  const u16* vsrc[2]; int vwr[2][8];
#pragma unroll
  for (int it=0; it<2; ++it){
    const int d0 = (w*2 + it)*8;
    vsrc[it] = qkv + (rowbase + lane)*3072 + 2048 + h*64 + d0;
#pragma unroll
    for (int j=0;j<8;++j){
      const int d = d0 + j;
      vwr[it][j] = d*128 + (((lane>>3) ^ (d&7)) << 4) + (lane&7)*2;
    }
  }
  int kra[2][4];
#pragma unroll
  for (int st=0; st<2; ++st)
#pragma unroll
    for (int ds=0; ds<4; ++ds){
      const int key = st*32 + l32;
      kra[st][ds] = key*128 + (((ds*2 + hi) ^ (key&7)) << 4);
    }
  int vra[2][2][2];
#pragma unroll
  for (int st=0; st<2; ++st)
#pragma unroll
    for (int ks=0; ks<2; ++ks)
#pragma unroll
      for (int dt=0; dt<2; ++dt){
        const int d = dt*32 + l32;
        vra[st][ks][dt] = d*128 + (((st*4 + ks*2 + hi) ^ (d&7)) << 4);
      }

  const size_t KSTRIDE = (size_t)64*3072;

  u16x8 kA[2], vA[2], kB[2], vB[2];
#pragma unroll
  for (int it=0; it<2; ++it){
    kA[it] = *reinterpret_cast<const u16x8*>(ksrc[it]);
    vA[it] = *reinterpret_cast<const u16x8*>(vsrc[it]);
  }

  float l_part = 0.f;
  f32x16 oacc[2] = {};

  auto step = [&](u16x8 (&kk)[2], u16x8 (&vv)[2], int kbn,
                  u16x8 (&kn)[2], u16x8 (&vn)[2]){
#pragma unroll
    for (int it=0; it<2; ++it){
      *reinterpret_cast<u16x8*>((char*)Kl + kwr[it]) = kk[it];
#pragma unroll
      for (int j=0;j<8;++j)
        *reinterpret_cast<u16*>((char*)Vt + vwr[it][j]) = vv[it][j];
    }
    __syncthreads();
    {
      const size_t off = (size_t)kbn * KSTRIDE;
#pragma unroll
      for (int it=0; it<2; ++it){
        kn[it] = *reinterpret_cast<const u16x8*>(ksrc[it] + off);
        vn[it] = *reinterpret_cast<const u16x8*>(vsrc[it] + off);
      }
    }
    f32x16 sacc[2] = {};
#pragma unroll
    for (int st=0; st<2; ++st)
#pragma unroll
      for (int ds=0; ds<4; ++ds){
        const bf16x8 af = *reinterpret_cast<const bf16x8*>((char*)Kl + kra[st][ds]);
        sacc[st] = __builtin_amdgcn_mfma_f32_32x32x16_bf16(af, qf[ds], sacc[st], 0,0,0);
      }
#pragma unroll
    for (int st=0; st<2; ++st)
#pragma unroll
      for (int r=0;r<16;++r){
        const float pv = __expf(sacc[st][r]);
        sacc[st][r] = pv;
        l_part += pv;
      }
#pragma unroll
    for (int st=0; st<2; ++st){
      unsigned wd[8];
#pragma unroll
      for (int m=0;m<8;++m)
        wd[m] = cvt_pk_bf16(sacc[st][2*m], sacc[st][2*m+1]);
      permlane32_swap(wd[0], wd[2]);
      permlane32_swap(wd[1], wd[3]);
      permlane32_swap(wd[4], wd[6]);
      permlane32_swap(wd[5], wd[7]);
      u32x4 paw[2];
      paw[0] = u32x4{wd[0], wd[1], wd[2], wd[3]};
      paw[1] = u32x4{wd[4], wd[5], wd[6], wd[7]};
#pragma unroll
      for (int ks=0; ks<2; ++ks){
        const bf16x8 pa = *reinterpret_cast<const bf16x8*>(&paw[ks]);
#pragma unroll
        for (int dt=0; dt<2; ++dt){
          const bf16x8 vb = *reinterpret_cast<const bf16x8*>((char*)Vt + vra[st][ks][dt]);
          oacc[dt] = __builtin_amdgcn_mfma_f32_32x32x16_bf16(pa, vb, oacc[dt], 0,0,0);
        }
      }
    }
    __syncthreads();
  };

#pragma unroll 1
  for (int kb=0; kb<32; kb+=2){
    step(kA, vA, (kb+1 < 32 ? kb+1 : 31), kB, vB);
    step(kB, vB, (kb+2 < 32 ? kb+2 : 31), kA, vA);
  }

  const float l_run = l_part + __shfl_xor(l_part, 32);

#pragma unroll
  for (int r=0;r<16;++r){
    const int crow = (r&3) + 8*(r>>2) + 4*hi;
    const float li = __shfl(l_run, crow);
    const size_t grow = rowbase + qt*128 + w*32 + crow;
#pragma unroll
    for (int dt=0; dt<2; ++dt)
      AH[grow*2048 + h*64 + dt*32 + l32] = f2b(oacc[dt][r] / li);
  }
}

// ---------------- HGRN chunked scan (32 chunks of 64) --------------------------
__global__ __launch_bounds__(256) void scan_p1(
    const u16* __restrict__ FIG, float* __restrict__ cA, float* __restrict__ cH)
{
  const unsigned int idx = blockIdx.x*256u + threadIdx.x;
  const unsigned int c = idx & 1023u, chunk = (idx>>10)&(NCHUNK-1), b = idx>>15;
  float A = 1.f, h = 0.f;
  const size_t base = ((size_t)b*NTOK + chunk*CHLEN) * 3072;
  for (int t=0;t<CHLEN;++t){
    const float F = b2f(FIG[base + (size_t)t*3072 + c]);
    const float I = b2f(FIG[base + (size_t)t*3072 + 1024 + c]);
    const float f = sigm(F);
    const float il = I*sigm(I) * (1.f - f);
    A *= f;
    h = fmaf(f, h, il);
  }
  cA[idx] = A; cH[idx] = h;
}

__global__ __launch_bounds__(256) void scan_p2(
    const float* __restrict__ cA, const float* __restrict__ cH, float* __restrict__ Hinit)
{
  const unsigned int idx = blockIdx.x*256u + threadIdx.x;  // [0,2048)
  const unsigned int b = idx>>10, c = idx&1023u;
  float h = 0.f;
#pragma unroll
  for (int ch=0;ch<NCHUNK;++ch){
    const unsigned int q = (b*NCHUNK + ch)*1024 + c;
    Hinit[q] = h;
    h = fmaf(cA[q], h, cH[q]);
  }
}

__global__ __launch_bounds__(256) void scan_p3(
    const u16* __restrict__ FIG, const float* __restrict__ Hinit, u16* __restrict__ Hb)
{
  const unsigned int idx = blockIdx.x*256u + threadIdx.x;
  const unsigned int c = idx & 1023u, chunk = (idx>>10)&(NCHUNK-1), b = idx>>15;
  float h = Hinit[idx];
  const size_t base = ((size_t)b*NTOK + chunk*CHLEN) * 3072;
  const size_t obase = ((size_t)b*NTOK + chunk*CHLEN) * CDIM;
  for (int t=0;t<CHLEN;++t){
    const float F = b2f(FIG[base + (size_t)t*3072 + c]);
    const float I = b2f(FIG[base + (size_t)t*3072 + 1024 + c]);
    const float f = sigm(F);
    const float il = I*sigm(I) * (1.f - f);
    h = fmaf(f, h, il);
    Hb[obase + (size_t)t*CDIM + c] = f2b(h);
  }
}

// ---------------- HGRN post: per-head RMSNorm * gn * silu(G) -------------------
__global__ __launch_bounds__(256) void hgrn_post(
    const u16* __restrict__ Hb, const u16* __restrict__ FIG,
    const float* __restrict__ gn, u16* __restrict__ AH)
{
  const int row = blockIdx.x;
  const int t = threadIdx.x;
  float hv[4]; float ss = 0.f;
#pragma unroll
  for (int e=0;e<4;++e){
    hv[e] = b2f(Hb[(size_t)row*CDIM + t*4 + e]);
    ss = fmaf(hv[e], hv[e], ss);
  }
#pragma unroll
  for (int o=1;o<16;o<<=1) ss += __shfl_xor(ss, o);
  const float rinv = rsqrtf(ss*(1.f/64.f) + 1e-5f);
#pragma unroll
  for (int e=0;e<4;++e){
    const int c = t*4+e;
    const float g = b2f(FIG[(size_t)row*3072 + 2048 + c]);
    AH[(size_t)row*2048 + 1024 + c] = f2b(hv[e]*rinv*gn[c] * g*sigm(g));
  }
}

// ---------------- MLP activation: silu(gate)*val -------------------------------
__global__ __launch_bounds__(256) void act_kernel(
    const u16* __restrict__ U, u16* __restrict__ A)
{
  const unsigned int i = blockIdx.x*256u + threadIdx.x;
  const unsigned int r = i / INTERDIM, j = i % INTERDIM;
  const float g = b2f(U[(size_t)r*(2*INTERDIM) + j]);
  const float v = b2f(U[(size_t)r*(2*INTERDIM) + INTERDIM + j]);
  A[i] = f2b(g*sigm(g)*v);
}

__global__ __launch_bounds__(256) void fill_fail(float* __restrict__ out)
{
  const unsigned int i = blockIdx.x*256u + threadIdx.x;
  out[i] = 1234.5f;
}

// ---------------- host orchestration ------------------------------------------
// xw aliases the corresponding OUT section (residual accumulator IS the
// output) — store_out removed.
static void run_stream(hipStream_t stream,
    const float* Xin, const float* LNW, const float* LNB,
    const float* MAG, const float* LA, const float* LBw, const float* GN,
    float* mods, float* xw,
    u16* WqkvT, const u16* WpwT, const u16* WhgrnT,
    const u16* WgateT, const u16* WdownT,
    u16* x_norm, u16* v_h, u16* qkvb, u16* delta, u16* AH,
    float* cA, float* cH, float* Hinit, u16* U, u16* actb)
{
  u16* FIG    = qkvb;
  u16* Hb     = delta;
  u16* mlp_in = x_norm;

  lora_fold<<<4096,256,0,stream>>>(LA, LBw, MAG, WqkvT);

  ln_kernel<<<ROWS,256,0,stream>>>(Xin, LNW, LNB, mods, 0, 1024, x_norm, v_h, xw);

  // attention branch -> AH[:,0:1024]
  gemm_bt<<<dim3(12,16),512,0,stream>>>(x_norm, WqkvT, ROWS,3072,1024, 1, qkvb, nullptr, nullptr);
  attn_mfma<<<dim3(16,16,2),256,0,stream>>>(qkvb, AH);

  // HGRN branch -> AH[:,1024:2048]
  gemm_bt<<<dim3(12,16),512,0,stream>>>(v_h, WhgrnT, ROWS,3072,1024, 1, FIG, nullptr, nullptr);
  scan_p1<<<2*NCHUNK*1024/256,256,0,stream>>>(FIG, cA, cH);
  scan_p2<<<8,256,0,stream>>>(cA, cH, Hinit);
  scan_p3<<<2*NCHUNK*1024/256,256,0,stream>>>(FIG, Hinit, Hb);
  hgrn_post<<<ROWS,256,0,stream>>>(Hb, FIG, GN, AH);

  // fused proj+wo: xw += g_msa * (AH @ [Wproj;Wwo]^T), split-K=4
  gemm_bt<<<dim3(4,16,4),512,0,stream>>>(AH, WpwT, ROWS,1024,2048, 2, nullptr, xw, mods+2048);

  // MLP
  ln_kernel<<<ROWS,256,0,stream>>>(xw, LNW, LNB, mods, 3072, 4096, nullptr, mlp_in, nullptr);
  gemm_bt<<<dim3(22,16),512,0,stream>>>(mlp_in, WgateT, ROWS,5632,1024, 1, U, nullptr, nullptr);
  act_kernel<<<ROWS*INTERDIM/256,256,0,stream>>>(U, actb);
  // down-proj split-K=4: xw += g_mlp * (act @ Wdown^T)
  gemm_bt<<<dim3(4,16,4),512,0,stream>>>(actb, WdownT, ROWS,1024,2816, 2, nullptr, xw, mods+5120);
}

extern "C" void kernel_launch(void* const* d_in, const int* in_sizes, int n_in,
                              void* d_out, int out_size, void* d_ws, size_t ws_size,
                              hipStream_t stream)
{
  const float* X    = (const float*)d_in[0];
  const float* Y    = (const float*)d_in[1];
  const float* Cc   = (const float*)d_in[2];
  const float* GXW  = (const float*)d_in[3];
  const float* GXB  = (const float*)d_in[4];
  const float* GYW  = (const float*)d_in[5];
  const float* GYB  = (const float*)d_in[6];
  const float* ADAW = (const float*)d_in[7];
  const float* ADAB = (const float*)d_in[8];
  const float* XY_QKV = (const float*)d_in[9];
  const float* XY_MAG = (const float*)d_in[10];
  const float* XY_LA  = (const float*)d_in[11];
  const float* XY_LB  = (const float*)d_in[12];
  const float* XY_PROJ= (const float*)d_in[13];
  const float* YX_QKV = (const float*)d_in[14];
  const float* YX_MAG = (const float*)d_in[15];
  const float* YX_LA  = (const float*)d_in[16];
  const float* YX_LB  = (const float*)d_in[17];
  const float* YX_PROJ= (const float*)d_in[18];
  const float* AX_WI = (const float*)d_in[19];
  const float* AX_WF = (const float*)d_in[20];
  const float* AX_WG = (const float*)d_in[21];
  const float* AX_WO = (const float*)d_in[22];
  const float* AX_GN = (const float*)d_in[23];
  const float* AY_WI = (const float*)d_in[24];
  const float* AY_WF = (const float*)d_in[25];
  const float* AY_WG = (const float*)d_in[26];
  const float* AY_WO = (const float*)d_in[27];
  const float* AY_GN = (const float*)d_in[28];
  const float* MX_GATE = (const float*)d_in[29];
  const float* MX_DOWN = (const float*)d_in[30];
  const float* MY_GATE = (const float*)d_in[31];
  const float* MY_DOWN = (const float*)d_in[32];
  float* OUT = (float*)d_out;

  char* p = (char*)d_ws;
  size_t off = 0;
  auto alloc = [&](size_t bytes)->char*{
    char* r = p + off;
    off = (off + bytes + 255) & ~(size_t)255;
    return r;
  };
  float* mods  = (float*)alloc(2*MODS_STRIDE*sizeof(float));
  u16* WqkvT0  = (u16*)alloc((size_t)3072*1024*2);
  u16* WqkvT1  = (u16*)alloc((size_t)3072*1024*2);
  u16* WpwT0   = (u16*)alloc((size_t)1024*2048*2);
  u16* WpwT1   = (u16*)alloc((size_t)1024*2048*2);
  u16* WhgrnT0 = (u16*)alloc((size_t)3072*1024*2);
  u16* WhgrnT1 = (u16*)alloc((size_t)3072*1024*2);
  u16* WgateT0 = (u16*)alloc((size_t)5632*1024*2);
  u16* WgateT1 = (u16*)alloc((size_t)5632*1024*2);
  u16* WdownT0 = (u16*)alloc((size_t)1024*2816*2);
  u16* WdownT1 = (u16*)alloc((size_t)1024*2816*2);
  u16* x_norm  = (u16*)alloc((size_t)ROWS*CDIM*2);
  u16* v_h     = (u16*)alloc((size_t)ROWS*CDIM*2);
  u16* qkvb    = (u16*)alloc((size_t)ROWS*3072*2);
  u16* delta   = (u16*)alloc((size_t)ROWS*CDIM*2);
  u16* AH      = (u16*)alloc((size_t)ROWS*2048*2);
  float* cA    = (float*)alloc((size_t)2*NCHUNK*1024*sizeof(float));
  float* cH    = (float*)alloc((size_t)2*NCHUNK*1024*sizeof(float));
  float* Hinit = (float*)alloc((size_t)2*NCHUNK*1024*sizeof(float));
  u16* U       = (u16*)alloc((size_t)ROWS*5632*2);
  u16* actb    = (u16*)alloc((size_t)ROWS*INTERDIM*2);

  if (off > ws_size){
    fill_fail<<<(2*ROWS*CDIM)/256,256,0,stream>>>(OUT);
    return;
  }

  ada_init<<<2*MODS_STRIDE/256,256,0,stream>>>(ADAB, mods);
  ada_split<<<dim3(MODS_STRIDE/256,16),256,0,stream>>>(Cc, ADAW, mods);

  TPack tp; int base = 0; int ndesc = 0;
  auto add = [&](const float* s, u16* d2, int rows, int cols, int dstride, int doff){
    tp.d[ndesc].src = s; tp.d[ndesc].dst = d2;
    tp.d[ndesc].rows = rows; tp.d[ndesc].cols = cols; tp.d[ndesc].base = base;
    tp.d[ndesc].dstride = dstride; tp.d[ndesc].doff = doff;
    base += (rows>>6)*(cols>>6); ++ndesc;
  };
  add(XY_QKV,  WqkvT0, 1024, 3072, 1024, 0);
  add(XY_PROJ, WpwT0,  1024, 1024, 2048, 0);
  add(AX_WO,   WpwT0,  1024, 1024, 2048, 1024);
  add(AX_WF, WhgrnT0,               1024, 1024, 1024, 0);
  add(AX_WI, WhgrnT0 + 1024*1024,   1024, 1024, 1024, 0);
  add(AX_WG, WhgrnT0 + 2*1024*1024, 1024, 1024, 1024, 0);
  add(MX_GATE, WgateT0, 1024, 5632, 1024, 0);
  add(MX_DOWN, WdownT0, 2816, 1024, 2816, 0);
  add(YX_QKV,  WqkvT1, 1024, 3072, 1024, 0);
  add(YX_PROJ, WpwT1,  1024, 1024, 2048, 0);
  add(AY_WO,   WpwT1,  1024, 1024, 2048, 1024);
  add(AY_WF, WhgrnT1,               1024, 1024, 1024, 0);
  add(AY_WI, WhgrnT1 + 1024*1024,   1024, 1024, 1024, 0);
  add(AY_WG, WhgrnT1 + 2*1024*1024, 1024, 1024, 1024, 0);
  add(MY_GATE, WgateT1, 1024, 5632, 1024, 0);
  add(MY_DOWN, WdownT1, 2816, 1024, 2816, 0);
  transpose_all<<<base,256,0,stream>>>(tp, ndesc);

  run_stream(stream, X, GXW, GXB, XY_MAG, XY_LA, XY_LB, AX_GN,
             mods, OUT,
             WqkvT0, WpwT0, WhgrnT0, WgateT0, WdownT0,
             x_norm, v_h, qkvb, delta, AH,
             cA, cH, Hinit, U, actb);

  run_stream(stream, Y, GYW, GYB, YX_MAG, YX_LA, YX_LB, AY_GN,
             mods, OUT + (size_t)ROWS*CDIM,
             WqkvT1, WpwT1, WhgrnT1, WgateT1, WdownT1,
             x_norm, v_h, qkvb, delta, AH,
             cA, cH, Hinit, U, actb);
}